// Round 3
// baseline (3231.704 us; speedup 1.0000x reference)
//
#include <hip/hip_runtime.h>
#include <hip/hip_bf16.h>
#include <hip/hip_fp16.h>

#define N_NODES   100000
#define N_FEAT    512
#define HIDDEN    64
#define N_CLASSES 40
#define KITER     10
#define ALPHA     0.1f
#define ZP        64      // padded fp16 row pitch: 128 B -> one cacheline per row
#define HPITCH    72      // LDS h pitch in halves (144 B) to break bank conflicts
#define NXCD      8
#define WIN       (N_NODES / NXCD)    // 12500 dst nodes per XCD-owned window
#define SUBCAP    65536               // per-(window,xcd) sub-bucket capacity (exp. 50K)

typedef __attribute__((ext_vector_type(8))) short bf16x8;
typedef __attribute__((ext_vector_type(4))) float f32x4;

__device__ __forceinline__ float bf2f(unsigned short u) {
    union { unsigned int i; float f; } c;
    c.i = ((unsigned int)u) << 16;
    return c.f;
}
__device__ __forceinline__ unsigned short f2bf(float f) {
    union { float f; unsigned int u; } c; c.f = f;
    unsigned int r = c.u + 0x7FFFu + ((c.u >> 16) & 1u);   // RNE
    return (unsigned short)(r >> 16);
}

// ---------------- dtype detection (runs every call; data-driven, deterministic) ----
__global__ void zero_flags_kernel(int* __restrict__ flags) {
    if (threadIdx.x < 2) flags[threadIdx.x] = 0;
}

__global__ void detect_float_kernel(const unsigned short* __restrict__ w1raw,
                                    int* __restrict__ flags) {
    int i = blockIdx.x * blockDim.x + threadIdx.x;
    if (i < 32768) {
        unsigned short u = w1raw[i];
        if ((u & 0x7F80u) == 0x7F80u) atomicAdd(&flags[0], 1);
    }
}

__global__ void detect_edge_kernel(const int* __restrict__ ei, int* __restrict__ flags) {
    int i = blockIdx.x * blockDim.x + threadIdx.x;
    if (i < 2048) {
        if (ei[2 * i + 1] != 0) atomicAdd(&flags[1], 1);
    }
}

// ---------------- pack W1 into MFMA B-fragment order (bf16) ----------------
__global__ void pack_w1_kernel(const void* __restrict__ W1p, const int* __restrict__ flags,
                               unsigned short* __restrict__ pb) {
    int idx = blockIdx.x * 256 + threadIdx.x;   // 32768 total
    int j    = idx & 7;
    int lane = (idx >> 3) & 63;
    int ktnt = idx >> 9;            // nt*16 + kt
    int kt = ktnt & 15, nt = ktnt >> 4;
    int k = kt * 32 + (lane >> 4) * 8 + j;
    int n = nt * 16 + (lane & 15);
    unsigned short v;
    if (flags[0] > 0) v = f2bf(((const float*)W1p)[k * HIDDEN + n]);
    else              v = ((const unsigned short*)W1p)[k * HIDDEN + n];
    pb[idx] = v;
}

// ---------------- pack W2 (64x40) into B-frag order, N padded to 48 -------------
__global__ void pack_w2_kernel(const void* __restrict__ W2p, const int* __restrict__ flags,
                               unsigned short* __restrict__ pb2) {
    int idx = blockIdx.x * 256 + threadIdx.x;   // 3072 total
    if (idx >= 3072) return;
    int j    = idx & 7;
    int lane = (idx >> 3) & 63;
    int ktnt = idx >> 9;            // nt*2 + kt
    int kt = ktnt & 1, nt = ktnt >> 1;
    int k = kt * 32 + (lane >> 4) * 8 + j;
    int n = nt * 16 + (lane & 15);
    unsigned short v = 0;
    if (n < N_CLASSES) {
        if (flags[0] > 0) v = f2bf(((const float*)W2p)[k * N_CLASSES + n]);
        else              v = ((const unsigned short*)W2p)[k * N_CLASSES + n];
    }
    pb2[idx] = v;
}

// ---------------- MLP: h0 = relu(x@W1+b1)@W2+b2, both layers MFMA --------------
// Stores h0 (fp32, z-space) and y0 = dinv*h0 (fp16) for the rescaled propagation.
__global__ __launch_bounds__(256) void mlp_kernel(
    const void* __restrict__ xp,
    const unsigned short* __restrict__ pb,    // packed W1 B-frags
    const unsigned short* __restrict__ pb2,   // packed W2 B-frags
    const void* __restrict__ b1p,
    const void* __restrict__ b2p,
    const int* __restrict__ flags,
    const float* __restrict__ dinv,
    float* __restrict__ h0,
    __half* __restrict__ zh0)
{
    __shared__ unsigned short hsb[16 * HPITCH];   // h in bf16, 2.25 KB
    const int t    = threadIdx.x;
    const int wave = t >> 6;
    const int lane = t & 63;
    const int quad = lane >> 4;
    const int ml   = lane & 15;
    const int base = blockIdx.x * 16;
    const int isf32 = flags[0] > 0;

    const bf16x8* pbv = (const bf16x8*)pb;

    // ---- layer 1: MFMA 16x16x32, m=16 nodes, n-tile=wave ----
    f32x4 acc = {0.f, 0.f, 0.f, 0.f};
    if (!isf32) {
        const unsigned short* xrow = (const unsigned short*)xp
                                   + (size_t)(base + ml) * N_FEAT + quad * 8;
        #pragma unroll
        for (int kt = 0; kt < 16; ++kt) {
            bf16x8 a = *(const bf16x8*)(xrow + kt * 32);
            bf16x8 b = pbv[(wave * 16 + kt) * 64 + lane];
            acc = __builtin_amdgcn_mfma_f32_16x16x32_bf16(a, b, acc, 0, 0, 0);
        }
    } else {
        const float* xf = (const float*)xp + (size_t)(base + ml) * N_FEAT + quad * 8;
        #pragma unroll
        for (int kt = 0; kt < 16; ++kt) {
            float4 lo = *(const float4*)(xf + kt * 32);
            float4 hi = *(const float4*)(xf + kt * 32 + 4);
            bf16x8 a;
            a[0] = (short)f2bf(lo.x); a[1] = (short)f2bf(lo.y);
            a[2] = (short)f2bf(lo.z); a[3] = (short)f2bf(lo.w);
            a[4] = (short)f2bf(hi.x); a[5] = (short)f2bf(hi.y);
            a[6] = (short)f2bf(hi.z); a[7] = (short)f2bf(hi.w);
            bf16x8 b = pbv[(wave * 16 + kt) * 64 + lane];
            acc = __builtin_amdgcn_mfma_f32_16x16x32_bf16(a, b, acc, 0, 0, 0);
        }
    }

    // bias + relu -> LDS as bf16
    float b1v = isf32 ? ((const float*)b1p)[wave * 16 + ml]
                      : bf2f(((const unsigned short*)b1p)[wave * 16 + ml]);
    #pragma unroll
    for (int r = 0; r < 4; ++r)
        hsb[(quad * 4 + r) * HPITCH + wave * 16 + ml] = f2bf(fmaxf(acc[r] + b1v, 0.0f));
    __syncthreads();

    // ---- layer 2: MFMA, m=16 nodes, K=64 (2 k-tiles), n padded to 48 (3 tiles) ----
    if (wave < 3) {
        const bf16x8* pb2v = (const bf16x8*)pb2;
        f32x4 acc2 = {0.f, 0.f, 0.f, 0.f};
        #pragma unroll
        for (int kt = 0; kt < 2; ++kt) {
            bf16x8 a = *(const bf16x8*)(hsb + ml * HPITCH + kt * 32 + quad * 8);
            bf16x8 b = pb2v[(wave * 2 + kt) * 64 + lane];
            acc2 = __builtin_amdgcn_mfma_f32_16x16x32_bf16(a, b, acc2, 0, 0, 0);
        }
        int n = wave * 16 + ml;
        if (n < N_CLASSES) {
            float b2v = isf32 ? ((const float*)b2p)[n] : bf2f(((const unsigned short*)b2p)[n]);
            #pragma unroll
            for (int r = 0; r < 4; ++r) {
                int node = base + quad * 4 + r;
                float v = acc2[r] + b2v;
                h0[(size_t)node * N_CLASSES + n] = v;
                zh0[(size_t)node * ZP + n] = __float2half(v * dinv[node]);
            }
        }
    }
}

// ---------------- graph preprocessing ----------------
__global__ void zero_cnt_kernel(int* __restrict__ cnt, int* __restrict__ cur) {
    int i = blockIdx.x * blockDim.x + threadIdx.x;
    if (i < N_NODES) cnt[i] = 0;
    if (i < 65) cur[i] = 0;    // 64 sub-bucket cursors + 1 overflow cursor
}

__global__ void dinv_kernel(const int* __restrict__ cnt, float* __restrict__ dinv) {
    int i = blockIdx.x * blockDim.x + threadIdx.x;
    if (i < N_NODES) dinv[i] = rsqrtf((float)cnt[i] + 1.0f);  // +1 self-loop
}

// zero the pad row (index N_NODES) of both ping-pong y buffers; invalid-lane
// gathers in prop read this row and contribute exactly 0.
__global__ void zero_pad_kernel(__half* __restrict__ a, __half* __restrict__ b) {
    int t = threadIdx.x;
    if (t < ZP)            a[(size_t)N_NODES * ZP + t]        = __float2half(0.0f);
    else if (t < 2 * ZP)   b[(size_t)N_NODES * ZP + (t - ZP)] = __float2half(0.0f);
}

// shuffle-based exclusive scan: 4096 elems/tile, 4 barriers/tile, 25 tiles
__global__ __launch_bounds__(1024) void scan_kernel(
    const int* __restrict__ cnt, int* __restrict__ rptr, int* __restrict__ wpos, int E)
{
    __shared__ int wsum[16];
    __shared__ int carry_s, tiletot_s;
    const int t = threadIdx.x, wave = t >> 6, lane = t & 63;
    if (t == 0) carry_s = 0;
    __syncthreads();
    for (int base = 0; base < N_NODES; base += 4096) {
        int i0 = base + t * 4;
        int v0 = (i0 + 0 < N_NODES) ? cnt[i0 + 0] : 0;
        int v1 = (i0 + 1 < N_NODES) ? cnt[i0 + 1] : 0;
        int v2 = (i0 + 2 < N_NODES) ? cnt[i0 + 2] : 0;
        int v3 = (i0 + 3 < N_NODES) ? cnt[i0 + 3] : 0;
        int tl = v0 + v1 + v2 + v3;
        int sc = tl;
        #pragma unroll
        for (int off = 1; off < 64; off <<= 1) {
            int u = __shfl_up(sc, off, 64);
            if (lane >= off) sc += u;
        }
        if (lane == 63) wsum[wave] = sc;
        int wexcl = sc - tl;
        __syncthreads();
        if (wave == 0) {
            int wv = (lane < 16) ? wsum[lane] : 0;
            int ws = wv;
            #pragma unroll
            for (int off = 1; off < 16; off <<= 1) {
                int u = __shfl_up(ws, off, 64);
                if (lane >= off) ws += u;
            }
            if (lane < 16) wsum[lane] = ws - wv;   // exclusive
            if (lane == 15) tiletot_s = ws;        // inclusive tile total
        }
        __syncthreads();
        int P  = carry_s + wsum[wave] + wexcl;
        int e0 = P, e1 = P + v0, e2 = e1 + v1, e3 = e2 + v2;
        if (i0 + 0 < N_NODES) { rptr[i0 + 0] = e0; wpos[i0 + 0] = e0; }
        if (i0 + 1 < N_NODES) { rptr[i0 + 1] = e1; wpos[i0 + 1] = e1; }
        if (i0 + 2 < N_NODES) { rptr[i0 + 2] = e2; wpos[i0 + 2] = e2; }
        if (i0 + 3 < N_NODES) { rptr[i0 + 3] = e3; wpos[i0 + 3] = e3; }
        __syncthreads();
        if (t == 0) carry_s += tiletot_s;
        __syncthreads();
    }
    if (t == 0) rptr[N_NODES] = E;
}

// ---------------- Pass A: fused degree-count + window partition ----------------
// One linear scan of the edge list. Each edge -> 4-B pack (r | off<<17), appended
// (wave-aggregated cursor atomics) to sub-bucket (window, xcd). Sub-bucket tails
// are each written by ONE XCD -> sequential full-line writes, no RFO churn.
// Overflow (impossible for near-uniform dst at SUBCAP=64K vs E[50K]) appends
// int2(r,c) to ovf; drained in scatter_kernel. Correctness never depends on the
// bid->XCD heuristic.
__global__ __launch_bounds__(256) void partition_kernel(
    const int* __restrict__ ei, const int* __restrict__ flags,
    int* __restrict__ cnt, unsigned int* __restrict__ sub,
    int* __restrict__ cur, int2* __restrict__ ovf, int E)
{
    const int i64f = flags[1] == 0;
    const int lane = threadIdx.x & 63;
    const int xcd  = blockIdx.x & 7;
    const int waveg  = (blockIdx.x * 256 + threadIdx.x) >> 6;
    const int stride = ((2048 * 256) >> 6) * 64;     // 524288 edges per sweep

    for (int base = waveg * 64; base < E; base += stride) {
        int e = base + lane;
        bool valid = e < E;
        int c = 0, r = 0;
        if (valid) {
            c = i64f ? __builtin_nontemporal_load(ei + 2 * E + 2 * e)
                     : __builtin_nontemporal_load(ei + E + e);
            r = i64f ? __builtin_nontemporal_load(ei + 2 * e)
                     : __builtin_nontemporal_load(ei + e);
            atomicAdd(&cnt[c], 1);
        }
        int w = valid ? (c / WIN) : 8;
        unsigned pk = valid ? ((unsigned)r | ((unsigned)(c - w * WIN) << 17)) : 0u;
        #pragma unroll
        for (int ww = 0; ww < NXCD; ++ww) {
            unsigned long long m = __ballot(w == ww);
            if (!m) continue;
            int leader = __ffsll(m) - 1;
            int bpos = 0;
            if (lane == leader) bpos = atomicAdd(&cur[ww * 8 + xcd], (int)__popcll(m));
            bpos = __shfl(bpos, leader, 64);
            if (w == ww) {
                int rank = (int)__popcll(m & ((1ull << lane) - 1ull));
                unsigned p = (unsigned)(bpos + rank);
                if (p < SUBCAP) sub[(unsigned)(ww * 8 + xcd) * SUBCAP + p] = pk;
                else { int op = atomicAdd(cur + 64, 1); ovf[op] = make_int2(r, c); }
            }
        }
    }
}

// ---------------- Pass B: window-local scatter into CSR ----------------
// Window w handled by blocks bid%8==w (same XCD under round-robin dispatch).
// Sequential read of the window's ~1.6 MB compact payload; scatter confined to
// the 1.6 MB srcidx window + 50 KB wpos -> entire working set < 4 MB L2, lines
// fill completely before the end-of-kernel flush writes them back once.
__global__ __launch_bounds__(256) void scatter_kernel(
    const unsigned int* __restrict__ sub, const int* __restrict__ cur,
    const int2* __restrict__ ovf,
    int* __restrict__ wpos, int* __restrict__ srcidx)
{
    const int w = blockIdx.x & 7;
    const int tid64 = (blockIdx.x >> 3) * 256 + threadIdx.x;   // 0..65535
    int P[9];
    P[0] = 0;
    #pragma unroll
    for (int a = 0; a < 8; ++a) {
        int na = cur[w * 8 + a];
        na = na > SUBCAP ? SUBCAP : na;
        P[a + 1] = P[a] + na;
    }
    const int total = P[8];
    for (int v = tid64; v < total; v += 65536) {
        int a = 0;
        #pragma unroll
        for (int q = 1; q < 8; ++q) if (v >= P[q]) a = q;
        unsigned pk = sub[(unsigned)(w * 8 + a) * SUBCAP + (v - P[a])];
        int r = (int)(pk & 0x1FFFFu);
        int c = w * WIN + (int)(pk >> 17);
        int pos = atomicAdd(&wpos[c], 1);
        srcidx[pos] = r;
    }
    // overflow drain (empty for near-uniform dst distributions)
    int ov = cur[64];
    for (int i = tid64; i < ov; i += 65536) {
        int2 rc = ovf[i];
        if (rc.y / WIN == w) {
            int pos = atomicAdd(&wpos[rc.y], 1);
            srcidx[pos] = rc.x;
        }
    }
}

// ---------------- propagation on rescaled state y = dinv*z ----------------
// y_new[c] = dinv[c] * ( a*h0[c] + (1-a)*dinv[c]*( sum_edges y[src] + y[c] ) )
// Edge payload is just the int32 src index; invalid lanes gather the zeroed pad row.
__global__ __launch_bounds__(256) void prop_kernel(
    const __half* __restrict__ zh, const float* __restrict__ h0,
    const float* __restrict__ dinv, const int* __restrict__ rptr,
    const int* __restrict__ srcidx, __half* __restrict__ zout)
{
    const int wave = threadIdx.x >> 6;
    const int lane = threadIdx.x & 63;
    const int g    = lane >> 4;        // node subgroup 0..3
    const int l    = lane & 15;        // lane within group
    const int node = blockIdx.x * 16 + wave * 4 + g;
    const int c0   = l * 4;            // first class handled by this lane

    const int beg = rptr[node];
    const int end = rptr[node + 1];
    int nch = (end - beg + 15) >> 4;
    int m1    = max(nch, __shfl_xor(nch, 16, 64));
    int maxch = max(m1,  __shfl_xor(m1, 32, 64));

    // issue long-latency per-node loads early
    float di = dinv[node];
    uint2 yself = *(const uint2*)(zh + ((size_t)node << 6) + c0);
    float h00 = 0.f, h01 = 0.f, h02 = 0.f, h03 = 0.f;
    if (c0 < N_CLASSES) {
        const float* hp = h0 + (size_t)node * N_CLASSES + c0;
        h00 = hp[0]; h01 = hp[1]; h02 = hp[2]; h03 = hp[3];
    }

    float a0 = 0.f, a1 = 0.f, a2 = 0.f, a3 = 0.f;
    float b0 = 0.f, b1 = 0.f, b2 = 0.f, b3 = 0.f;

    for (int ch = 0; ch < maxch; ++ch) {
        int idx = beg + ch * 16 + l;
        int sw  = (idx < end) ? srcidx[idx] : N_NODES;   // pad row => +0

        #pragma unroll
        for (int i = 0; i < 16; i += 2) {
            int s0 = __shfl(sw, (g << 4) + i,     64);
            int s1 = __shfl(sw, (g << 4) + i + 1, 64);
            uint2 z0 = *(const uint2*)(zh + ((size_t)s0 << 6) + c0);
            uint2 z1 = *(const uint2*)(zh + ((size_t)s1 << 6) + c0);
            const __half2* p0 = (const __half2*)&z0;
            const __half2* p1 = (const __half2*)&z1;
            float2 f00 = __half22float2(p0[0]);
            float2 f01 = __half22float2(p0[1]);
            float2 f10 = __half22float2(p1[0]);
            float2 f11 = __half22float2(p1[1]);
            a0 += f00.x; a1 += f00.y; a2 += f01.x; a3 += f01.y;
            b0 += f10.x; b1 += f10.y; b2 += f11.x; b3 += f11.y;
        }
    }

    if (c0 < N_CLASSES) {
        const __half2* ps = (const __half2*)&yself;
        float2 s01 = __half22float2(ps[0]);
        float2 s23 = __half22float2(ps[1]);
        float kk = (1.0f - ALPHA) * di;
        float o0 = ALPHA * h00 + kk * (a0 + b0 + s01.x);
        float o1 = ALPHA * h01 + kk * (a1 + b1 + s01.y);
        float o2 = ALPHA * h02 + kk * (a2 + b2 + s23.x);
        float o3 = ALPHA * h03 + kk * (a3 + b3 + s23.y);
        __half2 q01 = __floats2half2_rn(di * o0, di * o1);
        __half2 q23 = __floats2half2_rn(di * o2, di * o3);
        uint2 st;
        st.x = *(unsigned int*)&q01;
        st.y = *(unsigned int*)&q23;
        *(uint2*)(zout + ((size_t)node << 6) + c0) = st;
    }
}

// ---------------- log_softmax + store (fp32 or bf16 per flags[0]) ----------------
__global__ __launch_bounds__(256) void lsm_kernel(
    const __half* __restrict__ zh, const float* __restrict__ dinv,
    const int* __restrict__ flags, void* __restrict__ outp)
{
    const int wave = threadIdx.x >> 6;
    const int lane = threadIdx.x & 63;
    const int node = blockIdx.x * 4 + wave;
    const int isf32 = flags[0] > 0;

    float di = dinv[node];
    float v = (lane < N_CLASSES)
            ? __half2float(zh[(size_t)node * ZP + lane]) / di : -1e30f;
    float m = v;
    #pragma unroll
    for (int o = 32; o; o >>= 1) m = fmaxf(m, __shfl_xor(m, o, 64));
    float e = (lane < N_CLASSES) ? expf(v - m) : 0.0f;
    float s = e;
    #pragma unroll
    for (int o = 32; o; o >>= 1) s += __shfl_xor(s, o, 64);
    float ls = logf(s);
    if (lane < N_CLASSES) {
        float r = v - m - ls;
        size_t idx = (size_t)node * N_CLASSES + lane;
        if (isf32) ((float*)outp)[idx] = r;
        else       ((__hip_bfloat16*)outp)[idx] = __float2bfloat16(r);
    }
}

extern "C" void kernel_launch(void* const* d_in, const int* in_sizes, int n_in,
                              void* d_out, int out_size, void* d_ws, size_t ws_size,
                              hipStream_t stream)
{
    const void* x  = d_in[0];
    const void* W1 = d_in[1];
    const void* b1 = d_in[2];
    const void* W2 = d_in[3];
    const void* b2 = d_in[4];
    const int* ei = (const int*)d_in[5];
    const int E = in_sizes[5] / 2;

    // workspace carve-up (256B aligned)
    char* ws = (char*)d_ws;
    size_t off = 0;
    auto carve = [&](size_t bytes) -> void* {
        void* p = ws + off;
        off = (off + bytes + 255) & ~(size_t)255;
        return p;
    };
    float*  h0    = (float*) carve((size_t)N_NODES * N_CLASSES * 4);
    __half* zhA   = (__half*)carve((size_t)(N_NODES + 1) * ZP * 2);
    __half* zhB   = (__half*)carve((size_t)(N_NODES + 1) * ZP * 2);
    int*    cnt   = (int*)   carve((size_t)N_NODES * 4);
    float*  dinv  = (float*) carve((size_t)N_NODES * 4);
    int*    rptr  = (int*)   carve((size_t)(N_NODES + 1) * 4);
    int*    wpos  = (int*)   carve((size_t)N_NODES * 4);
    int*    srcidx= (int*)   carve((size_t)E * 4);
    unsigned int* sub = (unsigned int*)carve((size_t)64 * SUBCAP * 4);  // 16.8 MB
    int*    cur   = (int*)   carve(65 * sizeof(int));
    unsigned short* pb  = (unsigned short*)carve(32768 * 2);
    unsigned short* pb2 = (unsigned short*)carve(3072 * 2);
    int*    flags = (int*)   carve(2 * sizeof(int));
    (void)ws_size; (void)n_in; (void)out_size;

    // ovf aliases the (currently dead) zhA/zhB region: 2*(N+1)*128 B = 25.6 MB,
    // enough for E int2 entries; zhA/zhB are first written AFTER scatter_kernel.
    int2* ovf = (int2*)zhA;

    const int nodeBlocks = N_NODES / 4;       // 25000
    const int mlpBlocks  = N_NODES / 16;      // 6250
    const int propBlocks = N_NODES / 16;      // 6250 (16 nodes per block)
    const int nThreads1  = (N_NODES + 255) / 256;

    // dtype detection + weight packing
    zero_flags_kernel<<<1, 64, 0, stream>>>(flags);
    detect_float_kernel<<<128, 256, 0, stream>>>((const unsigned short*)W1, flags);
    detect_edge_kernel<<<8, 256, 0, stream>>>(ei, flags);
    pack_w1_kernel<<<128, 256, 0, stream>>>(W1, flags, pb);
    pack_w2_kernel<<<12, 256, 0, stream>>>(W2, flags, pb2);

    // CSR-by-destination build: zero -> partition(+count) -> dinv -> scan -> scatter
    zero_cnt_kernel<<<nThreads1, 256, 0, stream>>>(cnt, cur);
    partition_kernel<<<2048, 256, 0, stream>>>(ei, flags, cnt, sub, cur, ovf, E);
    dinv_kernel<<<nThreads1, 256, 0, stream>>>(cnt, dinv);
    scan_kernel<<<1, 1024, 0, stream>>>(cnt, rptr, wpos, E);
    scatter_kernel<<<2048, 256, 0, stream>>>(sub, cur, ovf, wpos, srcidx);
    zero_pad_kernel<<<1, 128, 0, stream>>>(zhA, zhB);

    // MLP (both layers MFMA); stores h0 fp32 and y0 = dinv*h0 fp16
    mlp_kernel<<<mlpBlocks, 256, 0, stream>>>(x, pb, pb2, b1, b2, flags, dinv, h0, zhA);

    // K propagation steps (ping-pong fp16, rescaled state)
    const __half* zin = zhA;
    __half* zout = zhB;
    const __half* zlast = zhA;
    for (int it = 0; it < KITER; ++it) {
        prop_kernel<<<propBlocks, 256, 0, stream>>>(zin, h0, dinv, rptr, srcidx, zout);
        zlast = zout;
        zin = zout;
        zout = (zout == zhB) ? zhA : zhB;
    }

    lsm_kernel<<<nodeBlocks, 256, 0, stream>>>(zlast, dinv, flags, d_out);
}

// Round 4
// 1250.360 us; speedup vs baseline: 2.5846x; 2.5846x over previous
//
#include <hip/hip_runtime.h>
#include <hip/hip_bf16.h>
#include <hip/hip_fp16.h>

#define N_NODES   100000
#define N_FEAT    512
#define HIDDEN    64
#define N_CLASSES 40
#define KITER     10
#define ALPHA     0.1f
#define ZP        64      // padded fp16 row pitch: 128 B -> one cacheline per row
#define HPITCH    72      // LDS h pitch in halves (144 B) to break bank conflicts
#define NXCD      8
#define WIN       (N_NODES / NXCD)    // 12500 dst nodes per XCD-owned window
#define SUBCAP    65536               // per-(window,xcd) sub-bucket capacity (exp. 50K)
#define PARTB     2048                // partition blocks
#define CAP       384                 // LDS bucket capacity per window (exp. 195)

typedef __attribute__((ext_vector_type(8))) short bf16x8;
typedef __attribute__((ext_vector_type(4))) float f32x4;

__device__ __forceinline__ float bf2f(unsigned short u) {
    union { unsigned int i; float f; } c;
    c.i = ((unsigned int)u) << 16;
    return c.f;
}
__device__ __forceinline__ unsigned short f2bf(float f) {
    union { float f; unsigned int u; } c; c.f = f;
    unsigned int r = c.u + 0x7FFFu + ((c.u >> 16) & 1u);   // RNE
    return (unsigned short)(r >> 16);
}

// ---------------- dtype detection (runs every call; data-driven, deterministic) ----
__global__ void zero_flags_kernel(int* __restrict__ flags) {
    if (threadIdx.x < 2) flags[threadIdx.x] = 0;
}

__global__ void detect_float_kernel(const unsigned short* __restrict__ w1raw,
                                    int* __restrict__ flags) {
    int i = blockIdx.x * blockDim.x + threadIdx.x;
    if (i < 32768) {
        unsigned short u = w1raw[i];
        if ((u & 0x7F80u) == 0x7F80u) atomicAdd(&flags[0], 1);
    }
}

__global__ void detect_edge_kernel(const int* __restrict__ ei, int* __restrict__ flags) {
    int i = blockIdx.x * blockDim.x + threadIdx.x;
    if (i < 2048) {
        if (ei[2 * i + 1] != 0) atomicAdd(&flags[1], 1);
    }
}

// ---------------- pack W1 into MFMA B-fragment order (bf16) ----------------
__global__ void pack_w1_kernel(const void* __restrict__ W1p, const int* __restrict__ flags,
                               unsigned short* __restrict__ pb) {
    int idx = blockIdx.x * 256 + threadIdx.x;   // 32768 total
    int j    = idx & 7;
    int lane = (idx >> 3) & 63;
    int ktnt = idx >> 9;            // nt*16 + kt
    int kt = ktnt & 15, nt = ktnt >> 4;
    int k = kt * 32 + (lane >> 4) * 8 + j;
    int n = nt * 16 + (lane & 15);
    unsigned short v;
    if (flags[0] > 0) v = f2bf(((const float*)W1p)[k * HIDDEN + n]);
    else              v = ((const unsigned short*)W1p)[k * HIDDEN + n];
    pb[idx] = v;
}

// ---------------- pack W2 (64x40) into B-frag order, N padded to 48 -------------
__global__ void pack_w2_kernel(const void* __restrict__ W2p, const int* __restrict__ flags,
                               unsigned short* __restrict__ pb2) {
    int idx = blockIdx.x * 256 + threadIdx.x;   // 3072 total
    if (idx >= 3072) return;
    int j    = idx & 7;
    int lane = (idx >> 3) & 63;
    int ktnt = idx >> 9;            // nt*2 + kt
    int kt = ktnt & 1, nt = ktnt >> 1;
    int k = kt * 32 + (lane >> 4) * 8 + j;
    int n = nt * 16 + (lane & 15);
    unsigned short v = 0;
    if (n < N_CLASSES) {
        if (flags[0] > 0) v = f2bf(((const float*)W2p)[k * N_CLASSES + n]);
        else              v = ((const unsigned short*)W2p)[k * N_CLASSES + n];
    }
    pb2[idx] = v;
}

// ---------------- MLP: h0 = relu(x@W1+b1)@W2+b2, both layers MFMA --------------
// Stores h0 (fp32, z-space) and y0 = dinv*h0 (fp16) for the rescaled propagation.
__global__ __launch_bounds__(256) void mlp_kernel(
    const void* __restrict__ xp,
    const unsigned short* __restrict__ pb,    // packed W1 B-frags
    const unsigned short* __restrict__ pb2,   // packed W2 B-frags
    const void* __restrict__ b1p,
    const void* __restrict__ b2p,
    const int* __restrict__ flags,
    const float* __restrict__ dinv,
    float* __restrict__ h0,
    __half* __restrict__ zh0)
{
    __shared__ unsigned short hsb[16 * HPITCH];   // h in bf16, 2.25 KB
    const int t    = threadIdx.x;
    const int wave = t >> 6;
    const int lane = t & 63;
    const int quad = lane >> 4;
    const int ml   = lane & 15;
    const int base = blockIdx.x * 16;
    const int isf32 = flags[0] > 0;

    const bf16x8* pbv = (const bf16x8*)pb;

    // ---- layer 1: MFMA 16x16x32, m=16 nodes, n-tile=wave ----
    f32x4 acc = {0.f, 0.f, 0.f, 0.f};
    if (!isf32) {
        const unsigned short* xrow = (const unsigned short*)xp
                                   + (size_t)(base + ml) * N_FEAT + quad * 8;
        #pragma unroll
        for (int kt = 0; kt < 16; ++kt) {
            bf16x8 a = *(const bf16x8*)(xrow + kt * 32);
            bf16x8 b = pbv[(wave * 16 + kt) * 64 + lane];
            acc = __builtin_amdgcn_mfma_f32_16x16x32_bf16(a, b, acc, 0, 0, 0);
        }
    } else {
        const float* xf = (const float*)xp + (size_t)(base + ml) * N_FEAT + quad * 8;
        #pragma unroll
        for (int kt = 0; kt < 16; ++kt) {
            float4 lo = *(const float4*)(xf + kt * 32);
            float4 hi = *(const float4*)(xf + kt * 32 + 4);
            bf16x8 a;
            a[0] = (short)f2bf(lo.x); a[1] = (short)f2bf(lo.y);
            a[2] = (short)f2bf(lo.z); a[3] = (short)f2bf(lo.w);
            a[4] = (short)f2bf(hi.x); a[5] = (short)f2bf(hi.y);
            a[6] = (short)f2bf(hi.z); a[7] = (short)f2bf(hi.w);
            bf16x8 b = pbv[(wave * 16 + kt) * 64 + lane];
            acc = __builtin_amdgcn_mfma_f32_16x16x32_bf16(a, b, acc, 0, 0, 0);
        }
    }

    // bias + relu -> LDS as bf16
    float b1v = isf32 ? ((const float*)b1p)[wave * 16 + ml]
                      : bf2f(((const unsigned short*)b1p)[wave * 16 + ml]);
    #pragma unroll
    for (int r = 0; r < 4; ++r)
        hsb[(quad * 4 + r) * HPITCH + wave * 16 + ml] = f2bf(fmaxf(acc[r] + b1v, 0.0f));
    __syncthreads();

    // ---- layer 2: MFMA, m=16 nodes, K=64 (2 k-tiles), n padded to 48 (3 tiles) ----
    if (wave < 3) {
        const bf16x8* pb2v = (const bf16x8*)pb2;
        f32x4 acc2 = {0.f, 0.f, 0.f, 0.f};
        #pragma unroll
        for (int kt = 0; kt < 2; ++kt) {
            bf16x8 a = *(const bf16x8*)(hsb + ml * HPITCH + kt * 32 + quad * 8);
            bf16x8 b = pb2v[(wave * 2 + kt) * 64 + lane];
            acc2 = __builtin_amdgcn_mfma_f32_16x16x32_bf16(a, b, acc2, 0, 0, 0);
        }
        int n = wave * 16 + ml;
        if (n < N_CLASSES) {
            float b2v = isf32 ? ((const float*)b2p)[n] : bf2f(((const unsigned short*)b2p)[n]);
            #pragma unroll
            for (int r = 0; r < 4; ++r) {
                int node = base + quad * 4 + r;
                float v = acc2[r] + b2v;
                h0[(size_t)node * N_CLASSES + n] = v;
                zh0[(size_t)node * ZP + n] = __float2half(v * dinv[node]);
            }
        }
    }
}

// ---------------- graph preprocessing ----------------
__global__ void zero_cnt_kernel(int* __restrict__ cnt, int* __restrict__ cur) {
    int i = blockIdx.x * blockDim.x + threadIdx.x;
    if (i < N_NODES) cnt[i] = 0;
    if (i < 65) cur[i] = 0;    // 64 sub-bucket cursors + 1 overflow cursor
}

__global__ void dinv_kernel(const int* __restrict__ cnt, float* __restrict__ dinv) {
    int i = blockIdx.x * blockDim.x + threadIdx.x;
    if (i < N_NODES) dinv[i] = rsqrtf((float)cnt[i] + 1.0f);  // +1 self-loop
}

// zero the pad row (index N_NODES) of both ping-pong y buffers; invalid-lane
// gathers in prop read this row and contribute exactly 0.
__global__ void zero_pad_kernel(__half* __restrict__ a, __half* __restrict__ b) {
    int t = threadIdx.x;
    if (t < ZP)            a[(size_t)N_NODES * ZP + t]        = __float2half(0.0f);
    else if (t < 2 * ZP)   b[(size_t)N_NODES * ZP + (t - ZP)] = __float2half(0.0f);
}

// shuffle-based exclusive scan: 4096 elems/tile, 4 barriers/tile, 25 tiles
__global__ __launch_bounds__(1024) void scan_kernel(
    const int* __restrict__ cnt, int* __restrict__ rptr, int* __restrict__ wpos, int E)
{
    __shared__ int wsum[16];
    __shared__ int carry_s, tiletot_s;
    const int t = threadIdx.x, wave = t >> 6, lane = t & 63;
    if (t == 0) carry_s = 0;
    __syncthreads();
    for (int base = 0; base < N_NODES; base += 4096) {
        int i0 = base + t * 4;
        int v0 = (i0 + 0 < N_NODES) ? cnt[i0 + 0] : 0;
        int v1 = (i0 + 1 < N_NODES) ? cnt[i0 + 1] : 0;
        int v2 = (i0 + 2 < N_NODES) ? cnt[i0 + 2] : 0;
        int v3 = (i0 + 3 < N_NODES) ? cnt[i0 + 3] : 0;
        int tl = v0 + v1 + v2 + v3;
        int sc = tl;
        #pragma unroll
        for (int off = 1; off < 64; off <<= 1) {
            int u = __shfl_up(sc, off, 64);
            if (lane >= off) sc += u;
        }
        if (lane == 63) wsum[wave] = sc;
        int wexcl = sc - tl;
        __syncthreads();
        if (wave == 0) {
            int wv = (lane < 16) ? wsum[lane] : 0;
            int ws = wv;
            #pragma unroll
            for (int off = 1; off < 16; off <<= 1) {
                int u = __shfl_up(ws, off, 64);
                if (lane >= off) ws += u;
            }
            if (lane < 16) wsum[lane] = ws - wv;   // exclusive
            if (lane == 15) tiletot_s = ws;        // inclusive tile total
        }
        __syncthreads();
        int P  = carry_s + wsum[wave] + wexcl;
        int e0 = P, e1 = P + v0, e2 = e1 + v1, e3 = e2 + v2;
        if (i0 + 0 < N_NODES) { rptr[i0 + 0] = e0; wpos[i0 + 0] = e0; }
        if (i0 + 1 < N_NODES) { rptr[i0 + 1] = e1; wpos[i0 + 1] = e1; }
        if (i0 + 2 < N_NODES) { rptr[i0 + 2] = e2; wpos[i0 + 2] = e2; }
        if (i0 + 3 < N_NODES) { rptr[i0 + 3] = e3; wpos[i0 + 3] = e3; }
        __syncthreads();
        if (t == 0) carry_s += tiletot_s;
        __syncthreads();
    }
    if (t == 0) rptr[N_NODES] = E;
}

// ---------------- Pass A: LDS-staged window partition (+ fused degree count) ----
// Each block owns a static ~1563-edge slice, read once (linear, nontemporal).
// Edges append to 8 per-window LDS buckets via LDS atomics (exp. 195/window,
// CAP=384 ~ 14 sigma). After one barrier, 8 groups of 32 lanes flush each bucket
// with EXACTLY ONE global cursor atomic (16K total, no dependent chains) and a
// contiguous coalesced burst into the XCD-owned sub-bucket. Degree count fused
// (fire-and-forget atomics, latency hidden by the stream). Overflow (adversarial
// only) -> ovf list, drained in scatter. Correctness never depends on bid->XCD.
__global__ __launch_bounds__(256) void partition_kernel(
    const int* __restrict__ ei, const int* __restrict__ flags,
    int* __restrict__ cnt, unsigned int* __restrict__ sub,
    int* __restrict__ cur, int2* __restrict__ ovf, int E)
{
    __shared__ unsigned buf[NXCD][CAP];
    __shared__ int cnt_lds[NXCD];
    __shared__ unsigned base_s[NXCD];

    const int i64f = flags[1] == 0;
    const int xcd  = blockIdx.x & 7;
    const int per  = (E + PARTB - 1) / PARTB;
    const int e0   = blockIdx.x * per;
    const int e1   = min(e0 + per, E);

    if (threadIdx.x < NXCD) cnt_lds[threadIdx.x] = 0;
    __syncthreads();

    for (int e = e0 + threadIdx.x; e < e1; e += 256) {
        int c = i64f ? __builtin_nontemporal_load(ei + 2 * E + 2 * e)
                     : __builtin_nontemporal_load(ei + E + e);
        int r = i64f ? __builtin_nontemporal_load(ei + 2 * e)
                     : __builtin_nontemporal_load(ei + e);
        atomicAdd(&cnt[c], 1);
        int w = c / WIN;
        unsigned pk = (unsigned)r | ((unsigned)(c - w * WIN) << 17);
        int slot = atomicAdd(&cnt_lds[w], 1);
        if (slot < CAP) buf[w][slot] = pk;
        else { int op = atomicAdd(cur + 64, 1); ovf[op] = make_int2(r, c); }
    }
    __syncthreads();

    const int g   = threadIdx.x >> 5;      // window handled by this 32-lane group
    const int l32 = threadIdx.x & 31;
    const int n   = min(cnt_lds[g], CAP);
    if (l32 == 0 && n > 0) base_s[g] = (unsigned)atomicAdd(&cur[g * 8 + xcd], n);
    __syncthreads();
    if (n > 0) {
        unsigned base = base_s[g];
        unsigned bslot = (unsigned)(g * 8 + xcd) * SUBCAP;
        for (int i = l32; i < n; i += 32) {
            unsigned p = base + (unsigned)i;
            unsigned pk = buf[g][i];
            if (p < SUBCAP) sub[bslot + p] = pk;
            else {
                int op = atomicAdd(cur + 64, 1);
                ovf[op] = make_int2((int)(pk & 0x1FFFFu), g * WIN + (int)(pk >> 17));
            }
        }
    }
}

// ---------------- Pass B: window-local scatter into CSR ----------------
// Window w handled by blocks bid%8==w (same XCD under round-robin dispatch).
// Sequential read of the window's ~1.6 MB compact payload; scatter confined to
// the 1.6 MB srcidx window + 50 KB wpos -> entire working set < 4 MB L2, lines
// fill completely before the end-of-kernel flush writes them back once.
__global__ __launch_bounds__(256) void scatter_kernel(
    const unsigned int* __restrict__ sub, const int* __restrict__ cur,
    const int2* __restrict__ ovf,
    int* __restrict__ wpos, int* __restrict__ srcidx)
{
    const int w = blockIdx.x & 7;
    const int tid64 = (blockIdx.x >> 3) * 256 + threadIdx.x;   // 0..65535
    int P[9];
    P[0] = 0;
    #pragma unroll
    for (int a = 0; a < 8; ++a) {
        int na = cur[w * 8 + a];
        na = na > SUBCAP ? SUBCAP : na;
        P[a + 1] = P[a] + na;
    }
    const int total = P[8];
    for (int v = tid64; v < total; v += 65536) {
        int a = 0;
        #pragma unroll
        for (int q = 1; q < 8; ++q) if (v >= P[q]) a = q;
        unsigned pk = sub[(unsigned)(w * 8 + a) * SUBCAP + (v - P[a])];
        int r = (int)(pk & 0x1FFFFu);
        int c = w * WIN + (int)(pk >> 17);
        int pos = atomicAdd(&wpos[c], 1);
        srcidx[pos] = r;
    }
    // overflow drain (empty for near-uniform dst distributions)
    int ov = cur[64];
    for (int i = tid64; i < ov; i += 65536) {
        int2 rc = ovf[i];
        if (rc.y / WIN == w) {
            int pos = atomicAdd(&wpos[rc.y], 1);
            srcidx[pos] = rc.x;
        }
    }
}

// ---------------- propagation on rescaled state y = dinv*z ----------------
// y_new[c] = dinv[c] * ( a*h0[c] + (1-a)*dinv[c]*( sum_edges y[src] + y[c] ) )
// Edge payload is just the int32 src index; invalid lanes gather the zeroed pad row.
__global__ __launch_bounds__(256) void prop_kernel(
    const __half* __restrict__ zh, const float* __restrict__ h0,
    const float* __restrict__ dinv, const int* __restrict__ rptr,
    const int* __restrict__ srcidx, __half* __restrict__ zout)
{
    const int wave = threadIdx.x >> 6;
    const int lane = threadIdx.x & 63;
    const int g    = lane >> 4;        // node subgroup 0..3
    const int l    = lane & 15;        // lane within group
    const int node = blockIdx.x * 16 + wave * 4 + g;
    const int c0   = l * 4;            // first class handled by this lane

    const int beg = rptr[node];
    const int end = rptr[node + 1];
    int nch = (end - beg + 15) >> 4;
    int m1    = max(nch, __shfl_xor(nch, 16, 64));
    int maxch = max(m1,  __shfl_xor(m1, 32, 64));

    // issue long-latency per-node loads early
    float di = dinv[node];
    uint2 yself = *(const uint2*)(zh + ((size_t)node << 6) + c0);
    float h00 = 0.f, h01 = 0.f, h02 = 0.f, h03 = 0.f;
    if (c0 < N_CLASSES) {
        const float* hp = h0 + (size_t)node * N_CLASSES + c0;
        h00 = hp[0]; h01 = hp[1]; h02 = hp[2]; h03 = hp[3];
    }

    float a0 = 0.f, a1 = 0.f, a2 = 0.f, a3 = 0.f;
    float b0 = 0.f, b1 = 0.f, b2 = 0.f, b3 = 0.f;

    for (int ch = 0; ch < maxch; ++ch) {
        int idx = beg + ch * 16 + l;
        int sw  = (idx < end) ? srcidx[idx] : N_NODES;   // pad row => +0

        #pragma unroll
        for (int i = 0; i < 16; i += 2) {
            int s0 = __shfl(sw, (g << 4) + i,     64);
            int s1 = __shfl(sw, (g << 4) + i + 1, 64);
            uint2 z0 = *(const uint2*)(zh + ((size_t)s0 << 6) + c0);
            uint2 z1 = *(const uint2*)(zh + ((size_t)s1 << 6) + c0);
            const __half2* p0 = (const __half2*)&z0;
            const __half2* p1 = (const __half2*)&z1;
            float2 f00 = __half22float2(p0[0]);
            float2 f01 = __half22float2(p0[1]);
            float2 f10 = __half22float2(p1[0]);
            float2 f11 = __half22float2(p1[1]);
            a0 += f00.x; a1 += f00.y; a2 += f01.x; a3 += f01.y;
            b0 += f10.x; b1 += f10.y; b2 += f11.x; b3 += f11.y;
        }
    }

    if (c0 < N_CLASSES) {
        const __half2* ps = (const __half2*)&yself;
        float2 s01 = __half22float2(ps[0]);
        float2 s23 = __half22float2(ps[1]);
        float kk = (1.0f - ALPHA) * di;
        float o0 = ALPHA * h00 + kk * (a0 + b0 + s01.x);
        float o1 = ALPHA * h01 + kk * (a1 + b1 + s01.y);
        float o2 = ALPHA * h02 + kk * (a2 + b2 + s23.x);
        float o3 = ALPHA * h03 + kk * (a3 + b3 + s23.y);
        __half2 q01 = __floats2half2_rn(di * o0, di * o1);
        __half2 q23 = __floats2half2_rn(di * o2, di * o3);
        uint2 st;
        st.x = *(unsigned int*)&q01;
        st.y = *(unsigned int*)&q23;
        *(uint2*)(zout + ((size_t)node << 6) + c0) = st;
    }
}

// ---------------- log_softmax + store (fp32 or bf16 per flags[0]) ----------------
__global__ __launch_bounds__(256) void lsm_kernel(
    const __half* __restrict__ zh, const float* __restrict__ dinv,
    const int* __restrict__ flags, void* __restrict__ outp)
{
    const int wave = threadIdx.x >> 6;
    const int lane = threadIdx.x & 63;
    const int node = blockIdx.x * 4 + wave;
    const int isf32 = flags[0] > 0;

    float di = dinv[node];
    float v = (lane < N_CLASSES)
            ? __half2float(zh[(size_t)node * ZP + lane]) / di : -1e30f;
    float m = v;
    #pragma unroll
    for (int o = 32; o; o >>= 1) m = fmaxf(m, __shfl_xor(m, o, 64));
    float e = (lane < N_CLASSES) ? expf(v - m) : 0.0f;
    float s = e;
    #pragma unroll
    for (int o = 32; o; o >>= 1) s += __shfl_xor(s, o, 64);
    float ls = logf(s);
    if (lane < N_CLASSES) {
        float r = v - m - ls;
        size_t idx = (size_t)node * N_CLASSES + lane;
        if (isf32) ((float*)outp)[idx] = r;
        else       ((__hip_bfloat16*)outp)[idx] = __float2bfloat16(r);
    }
}

extern "C" void kernel_launch(void* const* d_in, const int* in_sizes, int n_in,
                              void* d_out, int out_size, void* d_ws, size_t ws_size,
                              hipStream_t stream)
{
    const void* x  = d_in[0];
    const void* W1 = d_in[1];
    const void* b1 = d_in[2];
    const void* W2 = d_in[3];
    const void* b2 = d_in[4];
    const int* ei = (const int*)d_in[5];
    const int E = in_sizes[5] / 2;

    // workspace carve-up (256B aligned)
    char* ws = (char*)d_ws;
    size_t off = 0;
    auto carve = [&](size_t bytes) -> void* {
        void* p = ws + off;
        off = (off + bytes + 255) & ~(size_t)255;
        return p;
    };
    float*  h0    = (float*) carve((size_t)N_NODES * N_CLASSES * 4);
    __half* zhA   = (__half*)carve((size_t)(N_NODES + 1) * ZP * 2);
    __half* zhB   = (__half*)carve((size_t)(N_NODES + 1) * ZP * 2);
    int*    cnt   = (int*)   carve((size_t)N_NODES * 4);
    float*  dinv  = (float*) carve((size_t)N_NODES * 4);
    int*    rptr  = (int*)   carve((size_t)(N_NODES + 1) * 4);
    int*    wpos  = (int*)   carve((size_t)N_NODES * 4);
    int*    srcidx= (int*)   carve((size_t)E * 4);
    unsigned int* sub = (unsigned int*)carve((size_t)64 * SUBCAP * 4);  // 16.8 MB
    int*    cur   = (int*)   carve(65 * sizeof(int));
    unsigned short* pb  = (unsigned short*)carve(32768 * 2);
    unsigned short* pb2 = (unsigned short*)carve(3072 * 2);
    int*    flags = (int*)   carve(2 * sizeof(int));
    (void)ws_size; (void)n_in; (void)out_size;

    // ovf aliases the (currently dead) zhA/zhB region: 2*(N+1)*128 B = 25.6 MB,
    // enough for E int2 entries; zhA/zhB are first written AFTER scatter_kernel.
    int2* ovf = (int2*)zhA;

    const int nodeBlocks = N_NODES / 4;       // 25000
    const int mlpBlocks  = N_NODES / 16;      // 6250
    const int propBlocks = N_NODES / 16;      // 6250 (16 nodes per block)
    const int nThreads1  = (N_NODES + 255) / 256;

    // dtype detection + weight packing
    zero_flags_kernel<<<1, 64, 0, stream>>>(flags);
    detect_float_kernel<<<128, 256, 0, stream>>>((const unsigned short*)W1, flags);
    detect_edge_kernel<<<8, 256, 0, stream>>>(ei, flags);
    pack_w1_kernel<<<128, 256, 0, stream>>>(W1, flags, pb);
    pack_w2_kernel<<<12, 256, 0, stream>>>(W2, flags, pb2);

    // CSR-by-destination build: zero -> partition(+count) -> dinv -> scan -> scatter
    zero_cnt_kernel<<<nThreads1, 256, 0, stream>>>(cnt, cur);
    partition_kernel<<<PARTB, 256, 0, stream>>>(ei, flags, cnt, sub, cur, ovf, E);
    dinv_kernel<<<nThreads1, 256, 0, stream>>>(cnt, dinv);
    scan_kernel<<<1, 1024, 0, stream>>>(cnt, rptr, wpos, E);
    scatter_kernel<<<2048, 256, 0, stream>>>(sub, cur, ovf, wpos, srcidx);
    zero_pad_kernel<<<1, 128, 0, stream>>>(zhA, zhB);

    // MLP (both layers MFMA); stores h0 fp32 and y0 = dinv*h0 fp16
    mlp_kernel<<<mlpBlocks, 256, 0, stream>>>(x, pb, pb2, b1, b2, flags, dinv, h0, zhA);

    // K propagation steps (ping-pong fp16, rescaled state)
    const __half* zin = zhA;
    __half* zout = zhB;
    const __half* zlast = zhA;
    for (int it = 0; it < KITER; ++it) {
        prop_kernel<<<propBlocks, 256, 0, stream>>>(zin, h0, dinv, rptr, srcidx, zout);
        zlast = zout;
        zin = zout;
        zout = (zout == zhB) ? zhA : zhB;
    }

    lsm_kernel<<<nodeBlocks, 256, 0, stream>>>(zlast, dinv, flags, d_out);
}

// Round 5
// 1074.480 us; speedup vs baseline: 3.0077x; 1.1637x over previous
//
#include <hip/hip_runtime.h>
#include <hip/hip_bf16.h>
#include <hip/hip_fp16.h>

#define N_NODES   100000
#define N_FEAT    512
#define HIDDEN    64
#define N_CLASSES 40
#define KITER     10
#define ALPHA     0.1f
#define ZP        64      // padded fp16 row pitch: 128 B -> one cacheline per row
#define HPITCH    72      // LDS h pitch in halves (144 B) to break bank conflicts
#define NXCD      8
#define WIN       (N_NODES / NXCD)    // 12500 dst nodes per XCD-owned window
#define SUBCAP    65536               // per-(window,xcd) sub-bucket capacity (exp. 50K)
#define PARTB     2048                // partition blocks
#define CAP       384                 // LDS bucket capacity per window (exp. 195)

typedef __attribute__((ext_vector_type(8))) short bf16x8;
typedef __attribute__((ext_vector_type(4))) float f32x4;

__device__ __forceinline__ float bf2f(unsigned short u) {
    union { unsigned int i; float f; } c;
    c.i = ((unsigned int)u) << 16;
    return c.f;
}
__device__ __forceinline__ unsigned short f2bf(float f) {
    union { float f; unsigned int u; } c; c.f = f;
    unsigned int r = c.u + 0x7FFFu + ((c.u >> 16) & 1u);   // RNE
    return (unsigned short)(r >> 16);
}

// ---------------- dtype detection (runs every call; data-driven, deterministic) ----
__global__ void zero_cur_kernel(int* __restrict__ cur, int* __restrict__ flags) {
    int t = threadIdx.x;
    if (t < 65) cur[t] = 0;    // 64 sub-bucket cursors + 1 overflow cursor
    if (t >= 65 && t < 67) flags[t - 65] = 0;
}

__global__ void detect_float_kernel(const unsigned short* __restrict__ w1raw,
                                    int* __restrict__ flags) {
    int i = blockIdx.x * blockDim.x + threadIdx.x;
    if (i < 32768) {
        unsigned short u = w1raw[i];
        if ((u & 0x7F80u) == 0x7F80u) atomicAdd(&flags[0], 1);
    }
}

__global__ void detect_edge_kernel(const int* __restrict__ ei, int* __restrict__ flags) {
    int i = blockIdx.x * blockDim.x + threadIdx.x;
    if (i < 2048) {
        if (ei[2 * i + 1] != 0) atomicAdd(&flags[1], 1);
    }
}

// ---------------- pack W1 into MFMA B-fragment order (bf16) ----------------
__global__ void pack_w1_kernel(const void* __restrict__ W1p, const int* __restrict__ flags,
                               unsigned short* __restrict__ pb) {
    int idx = blockIdx.x * 256 + threadIdx.x;   // 32768 total
    int j    = idx & 7;
    int lane = (idx >> 3) & 63;
    int ktnt = idx >> 9;            // nt*16 + kt
    int kt = ktnt & 15, nt = ktnt >> 4;
    int k = kt * 32 + (lane >> 4) * 8 + j;
    int n = nt * 16 + (lane & 15);
    unsigned short v;
    if (flags[0] > 0) v = f2bf(((const float*)W1p)[k * HIDDEN + n]);
    else              v = ((const unsigned short*)W1p)[k * HIDDEN + n];
    pb[idx] = v;
}

// ---------------- pack W2 (64x40) into B-frag order, N padded to 48 -------------
__global__ void pack_w2_kernel(const void* __restrict__ W2p, const int* __restrict__ flags,
                               unsigned short* __restrict__ pb2) {
    int idx = blockIdx.x * 256 + threadIdx.x;   // 3072 total
    if (idx >= 3072) return;
    int j    = idx & 7;
    int lane = (idx >> 3) & 63;
    int ktnt = idx >> 9;            // nt*2 + kt
    int kt = ktnt & 1, nt = ktnt >> 1;
    int k = kt * 32 + (lane >> 4) * 8 + j;
    int n = nt * 16 + (lane & 15);
    unsigned short v = 0;
    if (n < N_CLASSES) {
        if (flags[0] > 0) v = f2bf(((const float*)W2p)[k * N_CLASSES + n]);
        else              v = ((const unsigned short*)W2p)[k * N_CLASSES + n];
    }
    pb2[idx] = v;
}

// ---------------- MLP: h0 = relu(x@W1+b1)@W2+b2, both layers MFMA --------------
// Stores h0 (fp32, z-space) and y0 = dinv*h0 (fp16) for the rescaled propagation.
__global__ __launch_bounds__(256) void mlp_kernel(
    const void* __restrict__ xp,
    const unsigned short* __restrict__ pb,    // packed W1 B-frags
    const unsigned short* __restrict__ pb2,   // packed W2 B-frags
    const void* __restrict__ b1p,
    const void* __restrict__ b2p,
    const int* __restrict__ flags,
    const float* __restrict__ dinv,
    float* __restrict__ h0,
    __half* __restrict__ zh0)
{
    __shared__ unsigned short hsb[16 * HPITCH];   // h in bf16, 2.25 KB
    const int t    = threadIdx.x;
    const int wave = t >> 6;
    const int lane = t & 63;
    const int quad = lane >> 4;
    const int ml   = lane & 15;
    const int base = blockIdx.x * 16;
    const int isf32 = flags[0] > 0;

    const bf16x8* pbv = (const bf16x8*)pb;

    // ---- layer 1: MFMA 16x16x32, m=16 nodes, n-tile=wave ----
    f32x4 acc = {0.f, 0.f, 0.f, 0.f};
    if (!isf32) {
        const unsigned short* xrow = (const unsigned short*)xp
                                   + (size_t)(base + ml) * N_FEAT + quad * 8;
        #pragma unroll
        for (int kt = 0; kt < 16; ++kt) {
            bf16x8 a = *(const bf16x8*)(xrow + kt * 32);
            bf16x8 b = pbv[(wave * 16 + kt) * 64 + lane];
            acc = __builtin_amdgcn_mfma_f32_16x16x32_bf16(a, b, acc, 0, 0, 0);
        }
    } else {
        const float* xf = (const float*)xp + (size_t)(base + ml) * N_FEAT + quad * 8;
        #pragma unroll
        for (int kt = 0; kt < 16; ++kt) {
            float4 lo = *(const float4*)(xf + kt * 32);
            float4 hi = *(const float4*)(xf + kt * 32 + 4);
            bf16x8 a;
            a[0] = (short)f2bf(lo.x); a[1] = (short)f2bf(lo.y);
            a[2] = (short)f2bf(lo.z); a[3] = (short)f2bf(lo.w);
            a[4] = (short)f2bf(hi.x); a[5] = (short)f2bf(hi.y);
            a[6] = (short)f2bf(hi.z); a[7] = (short)f2bf(hi.w);
            bf16x8 b = pbv[(wave * 16 + kt) * 64 + lane];
            acc = __builtin_amdgcn_mfma_f32_16x16x32_bf16(a, b, acc, 0, 0, 0);
        }
    }

    // bias + relu -> LDS as bf16
    float b1v = isf32 ? ((const float*)b1p)[wave * 16 + ml]
                      : bf2f(((const unsigned short*)b1p)[wave * 16 + ml]);
    #pragma unroll
    for (int r = 0; r < 4; ++r)
        hsb[(quad * 4 + r) * HPITCH + wave * 16 + ml] = f2bf(fmaxf(acc[r] + b1v, 0.0f));
    __syncthreads();

    // ---- layer 2: MFMA, m=16 nodes, K=64 (2 k-tiles), n padded to 48 (3 tiles) ----
    if (wave < 3) {
        const bf16x8* pb2v = (const bf16x8*)pb2;
        f32x4 acc2 = {0.f, 0.f, 0.f, 0.f};
        #pragma unroll
        for (int kt = 0; kt < 2; ++kt) {
            bf16x8 a = *(const bf16x8*)(hsb + ml * HPITCH + kt * 32 + quad * 8);
            bf16x8 b = pb2v[(wave * 2 + kt) * 64 + lane];
            acc2 = __builtin_amdgcn_mfma_f32_16x16x32_bf16(a, b, acc2, 0, 0, 0);
        }
        int n = wave * 16 + ml;
        if (n < N_CLASSES) {
            float b2v = isf32 ? ((const float*)b2p)[n] : bf2f(((const unsigned short*)b2p)[n]);
            #pragma unroll
            for (int r = 0; r < 4; ++r) {
                int node = base + quad * 4 + r;
                float v = acc2[r] + b2v;
                h0[(size_t)node * N_CLASSES + n] = v;
                zh0[(size_t)node * ZP + n] = __float2half(v * dinv[node]);
            }
        }
    }
}

// zero the pad row (index N_NODES) of both ping-pong y buffers; invalid-lane
// gathers in prop read this row and contribute exactly 0.
__global__ void zero_pad_kernel(__half* __restrict__ a, __half* __restrict__ b) {
    int t = threadIdx.x;
    if (t < ZP)            a[(size_t)N_NODES * ZP + t]        = __float2half(0.0f);
    else if (t < 2 * ZP)   b[(size_t)N_NODES * ZP + (t - ZP)] = __float2half(0.0f);
}

// ---------------- Pass A: LDS-staged window partition (NO per-edge global atomics) --
// Each block owns a static ~1563-edge slice, read once (linear, nontemporal).
// Edges append to 8 per-window LDS buckets via LDS atomics. After one barrier,
// 8 groups of 32 lanes flush each bucket with one global cursor atomic (16K total)
// and a contiguous coalesced burst into the XCD-owned sub-bucket. Overflow
// (adversarial only) -> ovf list. Correctness never depends on bid->XCD mapping.
__global__ __launch_bounds__(256) void partition_kernel(
    const int* __restrict__ ei, const int* __restrict__ flags,
    unsigned int* __restrict__ sub,
    int* __restrict__ cur, int2* __restrict__ ovf, int E)
{
    __shared__ unsigned buf[NXCD][CAP];
    __shared__ int cnt_lds[NXCD];
    __shared__ unsigned base_s[NXCD];

    const int i64f = flags[1] == 0;
    const int xcd  = blockIdx.x & 7;
    const int per  = (E + PARTB - 1) / PARTB;
    const int e0   = blockIdx.x * per;
    const int e1   = min(e0 + per, E);

    if (threadIdx.x < NXCD) cnt_lds[threadIdx.x] = 0;
    __syncthreads();

    for (int e = e0 + threadIdx.x; e < e1; e += 256) {
        int c = i64f ? __builtin_nontemporal_load(ei + 2 * E + 2 * e)
                     : __builtin_nontemporal_load(ei + E + e);
        int r = i64f ? __builtin_nontemporal_load(ei + 2 * e)
                     : __builtin_nontemporal_load(ei + e);
        int w = c / WIN;
        unsigned pk = (unsigned)r | ((unsigned)(c - w * WIN) << 17);
        int slot = atomicAdd(&cnt_lds[w], 1);
        if (slot < CAP) buf[w][slot] = pk;
        else { int op = atomicAdd(cur + 64, 1); ovf[op] = make_int2(r, c); }
    }
    __syncthreads();

    const int g   = threadIdx.x >> 5;      // window handled by this 32-lane group
    const int l32 = threadIdx.x & 31;
    const int n   = min(cnt_lds[g], CAP);
    if (l32 == 0 && n > 0) base_s[g] = (unsigned)atomicAdd(&cur[g * 8 + xcd], n);
    __syncthreads();
    if (n > 0) {
        unsigned base = base_s[g];
        unsigned bslot = (unsigned)(g * 8 + xcd) * SUBCAP;
        for (int i = l32; i < n; i += 32) {
            unsigned p = base + (unsigned)i;
            unsigned pk = buf[g][i];
            if (p < SUBCAP) sub[bslot + p] = pk;
            else {
                int op = atomicAdd(cur + 64, 1);
                ovf[op] = make_int2((int)(pk & 0x1FFFFu), g * WIN + (int)(pk >> 17));
            }
        }
    }
}

// ---------------- Pass B: per-sub-bucket LDS histogram (degrees, no atomics) ----
// Block (w,s) histograms its sub-bucket's window offsets into 50 KB LDS, then
// writes hists[(w,s)][0..WIN) sequentially. ovf edges are folded into (w,7).
__global__ __launch_bounds__(1024) void hist_kernel(
    const unsigned int* __restrict__ sub, const int* __restrict__ cur,
    const int2* __restrict__ ovf, int* __restrict__ hists)
{
    __shared__ int h[WIN];   // 50 KB
    const int w = blockIdx.x & 7;
    const int s = blockIdx.x >> 3;
    for (int off = threadIdx.x; off < WIN; off += 1024) h[off] = 0;
    __syncthreads();
    int n = min(cur[w * 8 + s], SUBCAP);
    const unsigned int* sp = sub + (size_t)(w * 8 + s) * SUBCAP;
    for (int i = threadIdx.x; i < n; i += 1024)
        atomicAdd(&h[sp[i] >> 17], 1);
    if (s == 7) {
        int ov = cur[64];
        for (int i = threadIdx.x; i < ov; i += 1024) {
            int2 rc = ovf[i];
            int ww = rc.y / WIN;
            if (ww == w) atomicAdd(&h[rc.y - ww * WIN], 1);
        }
    }
    __syncthreads();
    for (int off = threadIdx.x; off < WIN; off += 1024)
        hists[(size_t)(w * 8 + s) * WIN + off] = h[off];
}

// ---------------- degree -> cnt + dinv (no atomics) ----------------
__global__ void cnt_kernel(const int* __restrict__ hists, int* __restrict__ cnt,
                           float* __restrict__ dinv) {
    int i = blockIdx.x * 256 + threadIdx.x;
    if (i >= N_NODES) return;
    int w = i / WIN, off = i - w * WIN;
    int c = 0;
    #pragma unroll
    for (int x = 0; x < 8; ++x) c += hists[(size_t)(w * 8 + x) * WIN + off];
    cnt[i] = c;
    dinv[i] = rsqrtf((float)c + 1.0f);  // +1 self-loop
}

// shuffle-based exclusive scan: 4096 elems/tile, 4 barriers/tile, 25 tiles
__global__ __launch_bounds__(1024) void scan_kernel(
    const int* __restrict__ cnt, int* __restrict__ rptr, int E)
{
    __shared__ int wsum[16];
    __shared__ int carry_s, tiletot_s;
    const int t = threadIdx.x, wave = t >> 6, lane = t & 63;
    if (t == 0) carry_s = 0;
    __syncthreads();
    for (int base = 0; base < N_NODES; base += 4096) {
        int i0 = base + t * 4;
        int v0 = (i0 + 0 < N_NODES) ? cnt[i0 + 0] : 0;
        int v1 = (i0 + 1 < N_NODES) ? cnt[i0 + 1] : 0;
        int v2 = (i0 + 2 < N_NODES) ? cnt[i0 + 2] : 0;
        int v3 = (i0 + 3 < N_NODES) ? cnt[i0 + 3] : 0;
        int tl = v0 + v1 + v2 + v3;
        int sc = tl;
        #pragma unroll
        for (int off = 1; off < 64; off <<= 1) {
            int u = __shfl_up(sc, off, 64);
            if (lane >= off) sc += u;
        }
        if (lane == 63) wsum[wave] = sc;
        int wexcl = sc - tl;
        __syncthreads();
        if (wave == 0) {
            int wv = (lane < 16) ? wsum[lane] : 0;
            int ws = wv;
            #pragma unroll
            for (int off = 1; off < 16; off <<= 1) {
                int u = __shfl_up(ws, off, 64);
                if (lane >= off) ws += u;
            }
            if (lane < 16) wsum[lane] = ws - wv;   // exclusive
            if (lane == 15) tiletot_s = ws;        // inclusive tile total
        }
        __syncthreads();
        int P  = carry_s + wsum[wave] + wexcl;
        if (i0 + 0 < N_NODES) rptr[i0 + 0] = P;
        if (i0 + 1 < N_NODES) rptr[i0 + 1] = P + v0;
        if (i0 + 2 < N_NODES) rptr[i0 + 2] = P + v0 + v1;
        if (i0 + 3 < N_NODES) rptr[i0 + 3] = P + v0 + v1 + v2;
        __syncthreads();
        if (t == 0) carry_s += tiletot_s;
        __syncthreads();
    }
    if (t == 0) rptr[N_NODES] = E;
}

// ---------------- Pass C: race-free window-local scatter (no global atomics) ----
// Block (w,s): LDS cursors = rptr[node] + prefix over earlier sub-buckets' hists
// -> every (node, sub-bucket) owns a disjoint srcidx range. Scatter via LDS
// cursor atomics; all writes to window w come from XCD w (bid%8==w) -> lines
// fill in one coherent L2 and write back once. ovf drained by (w,7).
__global__ __launch_bounds__(1024) void scatter_kernel(
    const unsigned int* __restrict__ sub, const int* __restrict__ cur,
    const int* __restrict__ hists, const int2* __restrict__ ovf,
    const int* __restrict__ rptr, int* __restrict__ srcidx)
{
    __shared__ int curs[WIN];   // 50 KB
    const int w = blockIdx.x & 7;
    const int s = blockIdx.x >> 3;
    for (int off = threadIdx.x; off < WIN; off += 1024) {
        int base = rptr[w * WIN + off];
        for (int x = 0; x < s; ++x)
            base += hists[(size_t)(w * 8 + x) * WIN + off];
        curs[off] = base;
    }
    __syncthreads();
    int n = min(cur[w * 8 + s], SUBCAP);
    const unsigned int* sp = sub + (size_t)(w * 8 + s) * SUBCAP;
    for (int i = threadIdx.x; i < n; i += 1024) {
        unsigned pk = sp[i];
        int slot = atomicAdd(&curs[pk >> 17], 1);
        srcidx[slot] = (int)(pk & 0x1FFFFu);
    }
    if (s == 7) {
        int ov = cur[64];
        for (int i = threadIdx.x; i < ov; i += 1024) {
            int2 rc = ovf[i];
            int ww = rc.y / WIN;
            if (ww == w) {
                int slot = atomicAdd(&curs[rc.y - ww * WIN], 1);
                srcidx[slot] = rc.x;
            }
        }
    }
}

// ---------------- propagation on rescaled state y = dinv*z ----------------
// y_new[c] = dinv[c] * ( a*h0[c] + (1-a)*dinv[c]*( sum_edges y[src] + y[c] ) )
// Edge payload is just the int32 src index; invalid lanes gather the zeroed pad row.
__global__ __launch_bounds__(256) void prop_kernel(
    const __half* __restrict__ zh, const float* __restrict__ h0,
    const float* __restrict__ dinv, const int* __restrict__ rptr,
    const int* __restrict__ srcidx, __half* __restrict__ zout)
{
    const int wave = threadIdx.x >> 6;
    const int lane = threadIdx.x & 63;
    const int g    = lane >> 4;        // node subgroup 0..3
    const int l    = lane & 15;        // lane within group
    const int node = blockIdx.x * 16 + wave * 4 + g;
    const int c0   = l * 4;            // first class handled by this lane

    const int beg = rptr[node];
    const int end = rptr[node + 1];
    int nch = (end - beg + 15) >> 4;
    int m1    = max(nch, __shfl_xor(nch, 16, 64));
    int maxch = max(m1,  __shfl_xor(m1, 32, 64));

    // issue long-latency per-node loads early
    float di = dinv[node];
    uint2 yself = *(const uint2*)(zh + ((size_t)node << 6) + c0);
    float h00 = 0.f, h01 = 0.f, h02 = 0.f, h03 = 0.f;
    if (c0 < N_CLASSES) {
        const float* hp = h0 + (size_t)node * N_CLASSES + c0;
        h00 = hp[0]; h01 = hp[1]; h02 = hp[2]; h03 = hp[3];
    }

    float a0 = 0.f, a1 = 0.f, a2 = 0.f, a3 = 0.f;
    float b0 = 0.f, b1 = 0.f, b2 = 0.f, b3 = 0.f;

    for (int ch = 0; ch < maxch; ++ch) {
        int idx = beg + ch * 16 + l;
        int sw  = (idx < end) ? srcidx[idx] : N_NODES;   // pad row => +0

        #pragma unroll
        for (int i = 0; i < 16; i += 2) {
            int s0 = __shfl(sw, (g << 4) + i,     64);
            int s1 = __shfl(sw, (g << 4) + i + 1, 64);
            uint2 z0 = *(const uint2*)(zh + ((size_t)s0 << 6) + c0);
            uint2 z1 = *(const uint2*)(zh + ((size_t)s1 << 6) + c0);
            const __half2* p0 = (const __half2*)&z0;
            const __half2* p1 = (const __half2*)&z1;
            float2 f00 = __half22float2(p0[0]);
            float2 f01 = __half22float2(p0[1]);
            float2 f10 = __half22float2(p1[0]);
            float2 f11 = __half22float2(p1[1]);
            a0 += f00.x; a1 += f00.y; a2 += f01.x; a3 += f01.y;
            b0 += f10.x; b1 += f10.y; b2 += f11.x; b3 += f11.y;
        }
    }

    if (c0 < N_CLASSES) {
        const __half2* ps = (const __half2*)&yself;
        float2 s01 = __half22float2(ps[0]);
        float2 s23 = __half22float2(ps[1]);
        float kk = (1.0f - ALPHA) * di;
        float o0 = ALPHA * h00 + kk * (a0 + b0 + s01.x);
        float o1 = ALPHA * h01 + kk * (a1 + b1 + s01.y);
        float o2 = ALPHA * h02 + kk * (a2 + b2 + s23.x);
        float o3 = ALPHA * h03 + kk * (a3 + b3 + s23.y);
        __half2 q01 = __floats2half2_rn(di * o0, di * o1);
        __half2 q23 = __floats2half2_rn(di * o2, di * o3);
        uint2 st;
        st.x = *(unsigned int*)&q01;
        st.y = *(unsigned int*)&q23;
        *(uint2*)(zout + ((size_t)node << 6) + c0) = st;
    }
}

// ---------------- log_softmax + store (fp32 or bf16 per flags[0]) ----------------
__global__ __launch_bounds__(256) void lsm_kernel(
    const __half* __restrict__ zh, const float* __restrict__ dinv,
    const int* __restrict__ flags, void* __restrict__ outp)
{
    const int wave = threadIdx.x >> 6;
    const int lane = threadIdx.x & 63;
    const int node = blockIdx.x * 4 + wave;
    const int isf32 = flags[0] > 0;

    float di = dinv[node];
    float v = (lane < N_CLASSES)
            ? __half2float(zh[(size_t)node * ZP + lane]) / di : -1e30f;
    float m = v;
    #pragma unroll
    for (int o = 32; o; o >>= 1) m = fmaxf(m, __shfl_xor(m, o, 64));
    float e = (lane < N_CLASSES) ? expf(v - m) : 0.0f;
    float s = e;
    #pragma unroll
    for (int o = 32; o; o >>= 1) s += __shfl_xor(s, o, 64);
    float ls = logf(s);
    if (lane < N_CLASSES) {
        float r = v - m - ls;
        size_t idx = (size_t)node * N_CLASSES + lane;
        if (isf32) ((float*)outp)[idx] = r;
        else       ((__hip_bfloat16*)outp)[idx] = __float2bfloat16(r);
    }
}

extern "C" void kernel_launch(void* const* d_in, const int* in_sizes, int n_in,
                              void* d_out, int out_size, void* d_ws, size_t ws_size,
                              hipStream_t stream)
{
    const void* x  = d_in[0];
    const void* W1 = d_in[1];
    const void* b1 = d_in[2];
    const void* W2 = d_in[3];
    const void* b2 = d_in[4];
    const int* ei = (const int*)d_in[5];
    const int E = in_sizes[5] / 2;

    // workspace carve-up (256B aligned)
    char* ws = (char*)d_ws;
    size_t off = 0;
    auto carve = [&](size_t bytes) -> void* {
        void* p = ws + off;
        off = (off + bytes + 255) & ~(size_t)255;
        return p;
    };
    float*  h0    = (float*) carve((size_t)N_NODES * N_CLASSES * 4);
    __half* zhA   = (__half*)carve((size_t)(N_NODES + 1) * ZP * 2);
    __half* zhB   = (__half*)carve((size_t)(N_NODES + 1) * ZP * 2);
    int*    cnt   = (int*)   carve((size_t)N_NODES * 4);
    float*  dinv  = (float*) carve((size_t)N_NODES * 4);
    int*    rptr  = (int*)   carve((size_t)(N_NODES + 1) * 4);
    int*    srcidx= (int*)   carve((size_t)E * 4);
    unsigned int* sub = (unsigned int*)carve((size_t)64 * SUBCAP * 4);  // 16.8 MB
    int*    hists = (int*)   carve((size_t)64 * WIN * 4);               // 3.2 MB
    int*    cur   = (int*)   carve(65 * sizeof(int));
    unsigned short* pb  = (unsigned short*)carve(32768 * 2);
    unsigned short* pb2 = (unsigned short*)carve(3072 * 2);
    int*    flags = (int*)   carve(2 * sizeof(int));
    (void)ws_size; (void)n_in; (void)out_size;

    // ovf aliases the (currently dead) zhA/zhB region: 2*(N+1)*128 B = 25.6 MB,
    // enough for E int2 entries; zhA/zhB are first written AFTER scatter_kernel.
    int2* ovf = (int2*)zhA;

    const int nodeBlocks = N_NODES / 4;       // 25000
    const int mlpBlocks  = N_NODES / 16;      // 6250
    const int propBlocks = N_NODES / 16;      // 6250 (16 nodes per block)
    const int cntBlocks  = (N_NODES + 255) / 256;

    // dtype detection + weight packing
    zero_cur_kernel<<<1, 128, 0, stream>>>(cur, flags);
    detect_float_kernel<<<128, 256, 0, stream>>>((const unsigned short*)W1, flags);
    detect_edge_kernel<<<8, 256, 0, stream>>>(ei, flags);
    pack_w1_kernel<<<128, 256, 0, stream>>>(W1, flags, pb);
    pack_w2_kernel<<<12, 256, 0, stream>>>(W2, flags, pb2);

    // CSR build: partition -> hist -> cnt/dinv -> scan -> race-free scatter
    partition_kernel<<<PARTB, 256, 0, stream>>>(ei, flags, sub, cur, ovf, E);
    hist_kernel<<<64, 1024, 0, stream>>>(sub, cur, ovf, hists);
    cnt_kernel<<<cntBlocks, 256, 0, stream>>>(hists, cnt, dinv);
    scan_kernel<<<1, 1024, 0, stream>>>(cnt, rptr, E);
    scatter_kernel<<<64, 1024, 0, stream>>>(sub, cur, hists, ovf, rptr, srcidx);
    zero_pad_kernel<<<1, 128, 0, stream>>>(zhA, zhB);

    // MLP (both layers MFMA); stores h0 fp32 and y0 = dinv*h0 fp16
    mlp_kernel<<<mlpBlocks, 256, 0, stream>>>(x, pb, pb2, b1, b2, flags, dinv, h0, zhA);

    // K propagation steps (ping-pong fp16, rescaled state)
    const __half* zin = zhA;
    __half* zout = zhB;
    const __half* zlast = zhA;
    for (int it = 0; it < KITER; ++it) {
        prop_kernel<<<propBlocks, 256, 0, stream>>>(zin, h0, dinv, rptr, srcidx, zout);
        zlast = zout;
        zin = zout;
        zout = (zout == zhB) ? zhA : zhB;
    }

    lsm_kernel<<<nodeBlocks, 256, 0, stream>>>(zlast, dinv, flags, d_out);
}

// Round 6
// 1026.767 us; speedup vs baseline: 3.1475x; 1.0465x over previous
//
#include <hip/hip_runtime.h>
#include <hip/hip_bf16.h>
#include <hip/hip_fp16.h>

#define N_NODES   100000
#define N_FEAT    512
#define HIDDEN    64
#define N_CLASSES 40
#define KITER     10
#define ALPHA     0.1f
#define ZP        64      // padded fp16 row pitch: 128 B -> one cacheline per row
#define HPITCH    72      // LDS h pitch in halves (144 B) to break bank conflicts
#define NXCD      8
#define WIN       (N_NODES / NXCD)    // 12500 dst nodes per window
#define SUBCAP    65536               // per-(dstwin,srcwin) sub-bucket cap (exp. 50K)
#define PARTB     2048                // partition blocks
#define CAP       96                  // LDS bucket capacity per (dstwin,srcwin) (exp. 24)

typedef __attribute__((ext_vector_type(8))) short bf16x8;
typedef __attribute__((ext_vector_type(4))) float f32x4;

__device__ __forceinline__ float bf2f(unsigned short u) {
    union { unsigned int i; float f; } c;
    c.i = ((unsigned int)u) << 16;
    return c.f;
}
__device__ __forceinline__ unsigned short f2bf(float f) {
    union { float f; unsigned int u; } c; c.f = f;
    unsigned int r = c.u + 0x7FFFu + ((c.u >> 16) & 1u);   // RNE
    return (unsigned short)(r >> 16);
}

// ---------------- dtype detection (runs every call; data-driven, deterministic) ----
__global__ void zero_cur_kernel(int* __restrict__ cur, int* __restrict__ flags) {
    int t = threadIdx.x;
    if (t < 65) cur[t] = 0;    // 64 sub-bucket cursors + 1 overflow cursor
    if (t >= 65 && t < 67) flags[t - 65] = 0;
}

__global__ void detect_float_kernel(const unsigned short* __restrict__ w1raw,
                                    int* __restrict__ flags) {
    int i = blockIdx.x * blockDim.x + threadIdx.x;
    if (i < 32768) {
        unsigned short u = w1raw[i];
        if ((u & 0x7F80u) == 0x7F80u) atomicAdd(&flags[0], 1);
    }
}

__global__ void detect_edge_kernel(const int* __restrict__ ei, int* __restrict__ flags) {
    int i = blockIdx.x * blockDim.x + threadIdx.x;
    if (i < 2048) {
        if (ei[2 * i + 1] != 0) atomicAdd(&flags[1], 1);
    }
}

// ---------------- pack W1 into MFMA B-fragment order (bf16) ----------------
__global__ void pack_w1_kernel(const void* __restrict__ W1p, const int* __restrict__ flags,
                               unsigned short* __restrict__ pb) {
    int idx = blockIdx.x * 256 + threadIdx.x;   // 32768 total
    int j    = idx & 7;
    int lane = (idx >> 3) & 63;
    int ktnt = idx >> 9;            // nt*16 + kt
    int kt = ktnt & 15, nt = ktnt >> 4;
    int k = kt * 32 + (lane >> 4) * 8 + j;
    int n = nt * 16 + (lane & 15);
    unsigned short v;
    if (flags[0] > 0) v = f2bf(((const float*)W1p)[k * HIDDEN + n]);
    else              v = ((const unsigned short*)W1p)[k * HIDDEN + n];
    pb[idx] = v;
}

// ---------------- pack W2 (64x40) into B-frag order, N padded to 48 -------------
__global__ void pack_w2_kernel(const void* __restrict__ W2p, const int* __restrict__ flags,
                               unsigned short* __restrict__ pb2) {
    int idx = blockIdx.x * 256 + threadIdx.x;   // 3072 total
    if (idx >= 3072) return;
    int j    = idx & 7;
    int lane = (idx >> 3) & 63;
    int ktnt = idx >> 9;            // nt*2 + kt
    int kt = ktnt & 1, nt = ktnt >> 1;
    int k = kt * 32 + (lane >> 4) * 8 + j;
    int n = nt * 16 + (lane & 15);
    unsigned short v = 0;
    if (n < N_CLASSES) {
        if (flags[0] > 0) v = f2bf(((const float*)W2p)[k * N_CLASSES + n]);
        else              v = ((const unsigned short*)W2p)[k * N_CLASSES + n];
    }
    pb2[idx] = v;
}

// ---------------- MLP: h0 = relu(x@W1+b1)@W2+b2, both layers MFMA --------------
// v2: 64 nodes/block; each wave owns its own 16-node m-tile and loops all 4 W1
// n-tiles (kt-outer: one A-load feeds 4 MFMAs). x is read ONCE per wave (no
// cross-wave L2 re-read); 4x arithmetic intensity hides HBM latency.
__global__ __launch_bounds__(256) void mlp_kernel(
    const void* __restrict__ xp,
    const unsigned short* __restrict__ pb,    // packed W1 B-frags
    const unsigned short* __restrict__ pb2,   // packed W2 B-frags
    const void* __restrict__ b1p,
    const void* __restrict__ b2p,
    const int* __restrict__ flags,
    const float* __restrict__ dinv,
    float* __restrict__ h0,
    __half* __restrict__ zh0)
{
    __shared__ unsigned short hsb[4][16 * HPITCH];   // per-wave h tile, 9 KB
    const int t    = threadIdx.x;
    const int wave = t >> 6;
    const int lane = t & 63;
    const int quad = lane >> 4;
    const int ml   = lane & 15;
    const int mbase = blockIdx.x * 64 + wave * 16;   // this wave's 16 nodes
    const int isf32 = flags[0] > 0;
    const bool valid = mbase < N_NODES;

    const bf16x8* pbv = (const bf16x8*)pb;
    f32x4 acc[4];
    #pragma unroll
    for (int nt = 0; nt < 4; ++nt) acc[nt] = (f32x4){0.f, 0.f, 0.f, 0.f};

    if (valid) {
        if (!isf32) {
            const unsigned short* xrow = (const unsigned short*)xp
                                       + (size_t)(mbase + ml) * N_FEAT + quad * 8;
            #pragma unroll
            for (int kt = 0; kt < 16; ++kt) {
                bf16x8 a = *(const bf16x8*)(xrow + kt * 32);
                #pragma unroll
                for (int nt = 0; nt < 4; ++nt)
                    acc[nt] = __builtin_amdgcn_mfma_f32_16x16x32_bf16(
                        a, pbv[(nt * 16 + kt) * 64 + lane], acc[nt], 0, 0, 0);
            }
        } else {
            const float* xf = (const float*)xp + (size_t)(mbase + ml) * N_FEAT + quad * 8;
            #pragma unroll
            for (int kt = 0; kt < 16; ++kt) {
                float4 lo = *(const float4*)(xf + kt * 32);
                float4 hi = *(const float4*)(xf + kt * 32 + 4);
                bf16x8 a;
                a[0] = (short)f2bf(lo.x); a[1] = (short)f2bf(lo.y);
                a[2] = (short)f2bf(lo.z); a[3] = (short)f2bf(lo.w);
                a[4] = (short)f2bf(hi.x); a[5] = (short)f2bf(hi.y);
                a[6] = (short)f2bf(hi.z); a[7] = (short)f2bf(hi.w);
                #pragma unroll
                for (int nt = 0; nt < 4; ++nt)
                    acc[nt] = __builtin_amdgcn_mfma_f32_16x16x32_bf16(
                        a, pbv[(nt * 16 + kt) * 64 + lane], acc[nt], 0, 0, 0);
            }
        }

        // bias + relu -> this wave's LDS tile: h[node=quad*4+r][hid=nt*16+ml]
        #pragma unroll
        for (int nt = 0; nt < 4; ++nt) {
            float b1v = isf32 ? ((const float*)b1p)[nt * 16 + ml]
                              : bf2f(((const unsigned short*)b1p)[nt * 16 + ml]);
            #pragma unroll
            for (int r = 0; r < 4; ++r)
                hsb[wave][(quad * 4 + r) * HPITCH + nt * 16 + ml] =
                    f2bf(fmaxf(acc[nt][r] + b1v, 0.0f));
        }
    }
    __syncthreads();

    // ---- layer 2: per-wave, m=16 own nodes, K=64 (2 k-tiles), n padded to 48 ----
    if (valid) {
        const bf16x8* pb2v = (const bf16x8*)pb2;
        f32x4 acc2[3];
        #pragma unroll
        for (int n2 = 0; n2 < 3; ++n2) acc2[n2] = (f32x4){0.f, 0.f, 0.f, 0.f};
        #pragma unroll
        for (int kt = 0; kt < 2; ++kt) {
            bf16x8 a = *(const bf16x8*)(&hsb[wave][ml * HPITCH + kt * 32 + quad * 8]);
            #pragma unroll
            for (int n2 = 0; n2 < 3; ++n2)
                acc2[n2] = __builtin_amdgcn_mfma_f32_16x16x32_bf16(
                    a, pb2v[(n2 * 2 + kt) * 64 + lane], acc2[n2], 0, 0, 0);
        }
        #pragma unroll
        for (int n2 = 0; n2 < 3; ++n2) {
            int n = n2 * 16 + ml;
            if (n < N_CLASSES) {
                float b2v = isf32 ? ((const float*)b2p)[n]
                                  : bf2f(((const unsigned short*)b2p)[n]);
                #pragma unroll
                for (int r = 0; r < 4; ++r) {
                    int node = mbase + quad * 4 + r;
                    float v = acc2[n2][r] + b2v;
                    h0[(size_t)node * N_CLASSES + n] = v;
                    zh0[(size_t)node * ZP + n] = __float2half(v * dinv[node]);
                }
            }
        }
    }
}

// zero the pad row (index N_NODES) of both ping-pong y buffers; invalid-lane
// gathers in prop read this row and contribute exactly 0.
__global__ void zero_pad_kernel(__half* __restrict__ a, __half* __restrict__ b) {
    int t = threadIdx.x;
    if (t < ZP)            a[(size_t)N_NODES * ZP + t]        = __float2half(0.0f);
    else if (t < 2 * ZP)   b[(size_t)N_NODES * ZP + (t - ZP)] = __float2half(0.0f);
}

// ---------------- Pass A: LDS-staged (dstwin,srcwin) partition ----------------
// Bucket key is (dst window, SRC window): scatter (iterating srcwin in order)
// then emits each node's edge list sorted by source window, so prop sweeps the
// y-buffer monotonically in 1.6 MB windows (L2-capturable). Per-edge appends go
// to 64 LDS buckets (LDS atomics); one global cursor atomic per (block,bucket)
// (131K total, no dependent chains) + a coalesced tail burst. Overflow
// (adversarial only) -> ovf list. No per-edge global atomics anywhere.
__global__ __launch_bounds__(256) void partition_kernel(
    const int* __restrict__ ei, const int* __restrict__ flags,
    unsigned int* __restrict__ sub,
    int* __restrict__ cur, int2* __restrict__ ovf, int E)
{
    __shared__ unsigned buf[64][CAP];
    __shared__ int cnt_lds[64];
    __shared__ unsigned base_s[64];

    const int i64f = flags[1] == 0;
    const int per  = (E + PARTB - 1) / PARTB;
    const int e0   = blockIdx.x * per;
    const int e1   = min(e0 + per, E);

    if (threadIdx.x < 64) cnt_lds[threadIdx.x] = 0;
    __syncthreads();

    for (int e = e0 + threadIdx.x; e < e1; e += 256) {
        int c = i64f ? __builtin_nontemporal_load(ei + 2 * E + 2 * e)
                     : __builtin_nontemporal_load(ei + E + e);
        int r = i64f ? __builtin_nontemporal_load(ei + 2 * e)
                     : __builtin_nontemporal_load(ei + e);
        int wd = c / WIN;
        int ws = r / WIN;
        int b  = wd * 8 + ws;
        unsigned pk = (unsigned)r | ((unsigned)(c - wd * WIN) << 17);
        int slot = atomicAdd(&cnt_lds[b], 1);
        if (slot < CAP) buf[b][slot] = pk;
        else { int op = atomicAdd(cur + 64, 1); ovf[op] = make_int2(r, c); }
    }
    __syncthreads();

    const int g  = threadIdx.x >> 2;      // bucket handled by this 4-lane group
    const int l4 = threadIdx.x & 3;
    const int n  = min(cnt_lds[g], CAP);
    if (l4 == 0 && n > 0) base_s[g] = (unsigned)atomicAdd(&cur[g], n);
    __syncthreads();
    if (n > 0) {
        unsigned base = base_s[g];
        unsigned bslot = (unsigned)g * SUBCAP;
        for (int i = l4; i < n; i += 4) {
            unsigned p = base + (unsigned)i;
            unsigned pk = buf[g][i];
            if (p < SUBCAP) sub[bslot + p] = pk;
            else {
                int op = atomicAdd(cur + 64, 1);
                ovf[op] = make_int2((int)(pk & 0x1FFFFu),
                                    (g >> 3) * WIN + (int)(pk >> 17));
            }
        }
    }
}

// ---------------- Pass B: per-sub-bucket LDS histogram (degrees, no atomics) ----
// Block (w,s) histograms its sub-bucket's window offsets into 50 KB LDS, then
// writes hists[(w,s)][0..WIN) sequentially. ovf edges are folded into (w,7).
__global__ __launch_bounds__(1024) void hist_kernel(
    const unsigned int* __restrict__ sub, const int* __restrict__ cur,
    const int2* __restrict__ ovf, int* __restrict__ hists)
{
    __shared__ int h[WIN];   // 50 KB
    const int w = blockIdx.x & 7;
    const int s = blockIdx.x >> 3;
    for (int off = threadIdx.x; off < WIN; off += 1024) h[off] = 0;
    __syncthreads();
    int n = min(cur[w * 8 + s], SUBCAP);
    const unsigned int* sp = sub + (size_t)(w * 8 + s) * SUBCAP;
    for (int i = threadIdx.x; i < n; i += 1024)
        atomicAdd(&h[sp[i] >> 17], 1);
    if (s == 7) {
        int ov = cur[64];
        for (int i = threadIdx.x; i < ov; i += 1024) {
            int2 rc = ovf[i];
            int ww = rc.y / WIN;
            if (ww == w) atomicAdd(&h[rc.y - ww * WIN], 1);
        }
    }
    __syncthreads();
    for (int off = threadIdx.x; off < WIN; off += 1024)
        hists[(size_t)(w * 8 + s) * WIN + off] = h[off];
}

// ---------------- degree -> cnt + dinv (no atomics) ----------------
__global__ void cnt_kernel(const int* __restrict__ hists, int* __restrict__ cnt,
                           float* __restrict__ dinv) {
    int i = blockIdx.x * 256 + threadIdx.x;
    if (i >= N_NODES) return;
    int w = i / WIN, off = i - w * WIN;
    int c = 0;
    #pragma unroll
    for (int x = 0; x < 8; ++x) c += hists[(size_t)(w * 8 + x) * WIN + off];
    cnt[i] = c;
    dinv[i] = rsqrtf((float)c + 1.0f);  // +1 self-loop
}

// shuffle-based exclusive scan: 4096 elems/tile, 4 barriers/tile, 25 tiles
__global__ __launch_bounds__(1024) void scan_kernel(
    const int* __restrict__ cnt, int* __restrict__ rptr, int E)
{
    __shared__ int wsum[16];
    __shared__ int carry_s, tiletot_s;
    const int t = threadIdx.x, wave = t >> 6, lane = t & 63;
    if (t == 0) carry_s = 0;
    __syncthreads();
    for (int base = 0; base < N_NODES; base += 4096) {
        int i0 = base + t * 4;
        int v0 = (i0 + 0 < N_NODES) ? cnt[i0 + 0] : 0;
        int v1 = (i0 + 1 < N_NODES) ? cnt[i0 + 1] : 0;
        int v2 = (i0 + 2 < N_NODES) ? cnt[i0 + 2] : 0;
        int v3 = (i0 + 3 < N_NODES) ? cnt[i0 + 3] : 0;
        int tl = v0 + v1 + v2 + v3;
        int sc = tl;
        #pragma unroll
        for (int off = 1; off < 64; off <<= 1) {
            int u = __shfl_up(sc, off, 64);
            if (lane >= off) sc += u;
        }
        if (lane == 63) wsum[wave] = sc;
        int wexcl = sc - tl;
        __syncthreads();
        if (wave == 0) {
            int wv = (lane < 16) ? wsum[lane] : 0;
            int ws = wv;
            #pragma unroll
            for (int off = 1; off < 16; off <<= 1) {
                int u = __shfl_up(ws, off, 64);
                if (lane >= off) ws += u;
            }
            if (lane < 16) wsum[lane] = ws - wv;   // exclusive
            if (lane == 15) tiletot_s = ws;        // inclusive tile total
        }
        __syncthreads();
        int P  = carry_s + wsum[wave] + wexcl;
        if (i0 + 0 < N_NODES) rptr[i0 + 0] = P;
        if (i0 + 1 < N_NODES) rptr[i0 + 1] = P + v0;
        if (i0 + 2 < N_NODES) rptr[i0 + 2] = P + v0 + v1;
        if (i0 + 3 < N_NODES) rptr[i0 + 3] = P + v0 + v1 + v2;
        __syncthreads();
        if (t == 0) carry_s += tiletot_s;
        __syncthreads();
    }
    if (t == 0) rptr[N_NODES] = E;
}

// ---------------- Pass C: race-free window-local scatter (no global atomics) ----
// Block (w,s): LDS cursors = rptr[node] + prefix over earlier src-windows' hists
// -> every (node, srcwin) owns a disjoint srcidx range, AND iterating s=0..7
// leaves each node's list sorted by source window. All writes to window w come
// from one XCD (bid%8==w) -> lines fill in one coherent L2, write back once.
__global__ __launch_bounds__(1024) void scatter_kernel(
    const unsigned int* __restrict__ sub, const int* __restrict__ cur,
    const int* __restrict__ hists, const int2* __restrict__ ovf,
    const int* __restrict__ rptr, int* __restrict__ srcidx)
{
    __shared__ int curs[WIN];   // 50 KB
    const int w = blockIdx.x & 7;
    const int s = blockIdx.x >> 3;
    for (int off = threadIdx.x; off < WIN; off += 1024) {
        int base = rptr[w * WIN + off];
        for (int x = 0; x < s; ++x)
            base += hists[(size_t)(w * 8 + x) * WIN + off];
        curs[off] = base;
    }
    __syncthreads();
    int n = min(cur[w * 8 + s], SUBCAP);
    const unsigned int* sp = sub + (size_t)(w * 8 + s) * SUBCAP;
    for (int i = threadIdx.x; i < n; i += 1024) {
        unsigned pk = sp[i];
        int slot = atomicAdd(&curs[pk >> 17], 1);
        srcidx[slot] = (int)(pk & 0x1FFFFu);
    }
    if (s == 7) {
        int ov = cur[64];
        for (int i = threadIdx.x; i < ov; i += 1024) {
            int2 rc = ovf[i];
            int ww = rc.y / WIN;
            if (ww == w) {
                int slot = atomicAdd(&curs[rc.y - ww * WIN], 1);
                srcidx[slot] = rc.x;
            }
        }
    }
}

// ---------------- propagation on rescaled state y = dinv*z ----------------
// y_new[c] = dinv[c] * ( a*h0[c] + (1-a)*dinv[c]*( sum_edges y[src] + y[c] ) )
// Edge lists are src-window-sorted -> gathers sweep y monotonically (L2 capture).
// srcidx for the next chunk is prefetched to take the load off the critical path.
__global__ __launch_bounds__(256) void prop_kernel(
    const __half* __restrict__ zh, const float* __restrict__ h0,
    const float* __restrict__ dinv, const int* __restrict__ rptr,
    const int* __restrict__ srcidx, __half* __restrict__ zout)
{
    const int wave = threadIdx.x >> 6;
    const int lane = threadIdx.x & 63;
    const int g    = lane >> 4;        // node subgroup 0..3
    const int l    = lane & 15;        // lane within group
    const int node = blockIdx.x * 16 + wave * 4 + g;
    const int c0   = l * 4;            // first class handled by this lane

    const int beg = rptr[node];
    const int end = rptr[node + 1];
    int nch = (end - beg + 15) >> 4;
    int m1    = max(nch, __shfl_xor(nch, 16, 64));
    int maxch = max(m1,  __shfl_xor(m1, 32, 64));

    // issue long-latency per-node loads early
    float di = dinv[node];
    uint2 yself = *(const uint2*)(zh + ((size_t)node << 6) + c0);
    float h00 = 0.f, h01 = 0.f, h02 = 0.f, h03 = 0.f;
    if (c0 < N_CLASSES) {
        const float* hp = h0 + (size_t)node * N_CLASSES + c0;
        h00 = hp[0]; h01 = hp[1]; h02 = hp[2]; h03 = hp[3];
    }

    float a0 = 0.f, a1 = 0.f, a2 = 0.f, a3 = 0.f;
    float b0 = 0.f, b1 = 0.f, b2 = 0.f, b3 = 0.f;

    int idx0 = beg + l;
    int sw = (idx0 < end) ? srcidx[idx0] : N_NODES;   // pad row => +0

    for (int ch = 0; ch < maxch; ++ch) {
        // prefetch next chunk's srcidx before consuming this one
        int idxn = beg + (ch + 1) * 16 + l;
        int swn = (ch + 1 < maxch) ? ((idxn < end) ? srcidx[idxn] : N_NODES) : N_NODES;

        #pragma unroll
        for (int i = 0; i < 16; i += 2) {
            int s0 = __shfl(sw, (g << 4) + i,     64);
            int s1 = __shfl(sw, (g << 4) + i + 1, 64);
            uint2 z0 = *(const uint2*)(zh + ((size_t)s0 << 6) + c0);
            uint2 z1 = *(const uint2*)(zh + ((size_t)s1 << 6) + c0);
            const __half2* p0 = (const __half2*)&z0;
            const __half2* p1 = (const __half2*)&z1;
            float2 f00 = __half22float2(p0[0]);
            float2 f01 = __half22float2(p0[1]);
            float2 f10 = __half22float2(p1[0]);
            float2 f11 = __half22float2(p1[1]);
            a0 += f00.x; a1 += f00.y; a2 += f01.x; a3 += f01.y;
            b0 += f10.x; b1 += f10.y; b2 += f11.x; b3 += f11.y;
        }
        sw = swn;
    }

    if (c0 < N_CLASSES) {
        const __half2* ps = (const __half2*)&yself;
        float2 s01 = __half22float2(ps[0]);
        float2 s23 = __half22float2(ps[1]);
        float kk = (1.0f - ALPHA) * di;
        float o0 = ALPHA * h00 + kk * (a0 + b0 + s01.x);
        float o1 = ALPHA * h01 + kk * (a1 + b1 + s01.y);
        float o2 = ALPHA * h02 + kk * (a2 + b2 + s23.x);
        float o3 = ALPHA * h03 + kk * (a3 + b3 + s23.y);
        __half2 q01 = __floats2half2_rn(di * o0, di * o1);
        __half2 q23 = __floats2half2_rn(di * o2, di * o3);
        uint2 st;
        st.x = *(unsigned int*)&q01;
        st.y = *(unsigned int*)&q23;
        *(uint2*)(zout + ((size_t)node << 6) + c0) = st;
    }
}

// ---------------- log_softmax + store (fp32 or bf16 per flags[0]) ----------------
__global__ __launch_bounds__(256) void lsm_kernel(
    const __half* __restrict__ zh, const float* __restrict__ dinv,
    const int* __restrict__ flags, void* __restrict__ outp)
{
    const int wave = threadIdx.x >> 6;
    const int lane = threadIdx.x & 63;
    const int node = blockIdx.x * 4 + wave;
    const int isf32 = flags[0] > 0;

    float di = dinv[node];
    float v = (lane < N_CLASSES)
            ? __half2float(zh[(size_t)node * ZP + lane]) / di : -1e30f;
    float m = v;
    #pragma unroll
    for (int o = 32; o; o >>= 1) m = fmaxf(m, __shfl_xor(m, o, 64));
    float e = (lane < N_CLASSES) ? expf(v - m) : 0.0f;
    float s = e;
    #pragma unroll
    for (int o = 32; o; o >>= 1) s += __shfl_xor(s, o, 64);
    float ls = logf(s);
    if (lane < N_CLASSES) {
        float r = v - m - ls;
        size_t idx = (size_t)node * N_CLASSES + lane;
        if (isf32) ((float*)outp)[idx] = r;
        else       ((__hip_bfloat16*)outp)[idx] = __float2bfloat16(r);
    }
}

extern "C" void kernel_launch(void* const* d_in, const int* in_sizes, int n_in,
                              void* d_out, int out_size, void* d_ws, size_t ws_size,
                              hipStream_t stream)
{
    const void* x  = d_in[0];
    const void* W1 = d_in[1];
    const void* b1 = d_in[2];
    const void* W2 = d_in[3];
    const void* b2 = d_in[4];
    const int* ei = (const int*)d_in[5];
    const int E = in_sizes[5] / 2;

    // workspace carve-up (256B aligned)
    char* ws = (char*)d_ws;
    size_t off = 0;
    auto carve = [&](size_t bytes) -> void* {
        void* p = ws + off;
        off = (off + bytes + 255) & ~(size_t)255;
        return p;
    };
    float*  h0    = (float*) carve((size_t)N_NODES * N_CLASSES * 4);
    __half* zhA   = (__half*)carve((size_t)(N_NODES + 1) * ZP * 2);
    __half* zhB   = (__half*)carve((size_t)(N_NODES + 1) * ZP * 2);
    int*    cnt   = (int*)   carve((size_t)N_NODES * 4);
    float*  dinv  = (float*) carve((size_t)N_NODES * 4);
    int*    rptr  = (int*)   carve((size_t)(N_NODES + 1) * 4);
    int*    srcidx= (int*)   carve((size_t)E * 4);
    unsigned int* sub = (unsigned int*)carve((size_t)64 * SUBCAP * 4);  // 16.8 MB
    int*    hists = (int*)   carve((size_t)64 * WIN * 4);               // 3.2 MB
    int*    cur   = (int*)   carve(65 * sizeof(int));
    unsigned short* pb  = (unsigned short*)carve(32768 * 2);
    unsigned short* pb2 = (unsigned short*)carve(3072 * 2);
    int*    flags = (int*)   carve(2 * sizeof(int));
    (void)ws_size; (void)n_in; (void)out_size;

    // ovf aliases the (currently dead) zhA/zhB region: 2*(N+1)*128 B = 25.6 MB,
    // enough for E int2 entries; zhA/zhB are first written AFTER scatter_kernel.
    int2* ovf = (int2*)zhA;

    const int nodeBlocks = N_NODES / 4;            // 25000
    const int mlpBlocks  = (N_NODES + 63) / 64;    // 1563
    const int propBlocks = N_NODES / 16;           // 6250 (16 nodes per block)
    const int cntBlocks  = (N_NODES + 255) / 256;

    // dtype detection + weight packing
    zero_cur_kernel<<<1, 128, 0, stream>>>(cur, flags);
    detect_float_kernel<<<128, 256, 0, stream>>>((const unsigned short*)W1, flags);
    detect_edge_kernel<<<8, 256, 0, stream>>>(ei, flags);
    pack_w1_kernel<<<128, 256, 0, stream>>>(W1, flags, pb);
    pack_w2_kernel<<<12, 256, 0, stream>>>(W2, flags, pb2);

    // CSR build: partition -> hist -> cnt/dinv -> scan -> race-free scatter
    partition_kernel<<<PARTB, 256, 0, stream>>>(ei, flags, sub, cur, ovf, E);
    hist_kernel<<<64, 1024, 0, stream>>>(sub, cur, ovf, hists);
    cnt_kernel<<<cntBlocks, 256, 0, stream>>>(hists, cnt, dinv);
    scan_kernel<<<1, 1024, 0, stream>>>(cnt, rptr, E);
    scatter_kernel<<<64, 1024, 0, stream>>>(sub, cur, hists, ovf, rptr, srcidx);
    zero_pad_kernel<<<1, 128, 0, stream>>>(zhA, zhB);

    // MLP (both layers MFMA); stores h0 fp32 and y0 = dinv*h0 fp16
    mlp_kernel<<<mlpBlocks, 256, 0, stream>>>(x, pb, pb2, b1, b2, flags, dinv, h0, zhA);

    // K propagation steps (ping-pong fp16, rescaled state)
    const __half* zin = zhA;
    __half* zout = zhB;
    const __half* zlast = zhA;
    for (int it = 0; it < KITER; ++it) {
        prop_kernel<<<propBlocks, 256, 0, stream>>>(zin, h0, dinv, rptr, srcidx, zout);
        zlast = zout;
        zin = zout;
        zout = (zout == zhB) ? zhA : zhB;
    }

    lsm_kernel<<<nodeBlocks, 256, 0, stream>>>(zlast, dinv, flags, d_out);
}